// Round 7
// baseline (151.662 us; speedup 1.0000x reference)
//
#include <hip/hip_runtime.h>
#include <hip/hip_bf16.h>
#include <cstdint>
#include <cstddef>

#define D_MODEL 1024
#define NHEAD   16
#define HDIM    64
#define BB      2
#define TT      2048
#define MM      (BB*TT)    // 4096 rows
#define BHN     (BB*NHEAD) // 32

typedef __attribute__((ext_vector_type(8))) __bf16 bf16x8;
typedef __attribute__((ext_vector_type(4))) float  f32x4;
typedef __attribute__((ext_vector_type(8))) unsigned short u16x8;
typedef __attribute__((ext_vector_type(4))) unsigned short u16x4;

__device__ __forceinline__ unsigned short f2b(float f){
  __bf16 b = (__bf16)f;
  return __builtin_bit_cast(unsigned short, b);
}
__device__ __forceinline__ float b2f(unsigned short u){
  unsigned int x = ((unsigned int)u) << 16;
  return __builtin_bit_cast(float, x);
}

__device__ __forceinline__ f32x4 mfma16(bf16x8 a, bf16x8 b, f32x4 c){
  return __builtin_amdgcn_mfma_f32_16x16x32_bf16(a, b, c, 0, 0, 0);
}

// async global->LDS, 16B per lane; LDS dest = wave-uniform base + lane*16.
__device__ __forceinline__ void gload16(const void* g, void* lds){
  __builtin_amdgcn_global_load_lds((const __attribute__((address_space(1))) void*)g,
                                   (__attribute__((address_space(3))) void*)lds, 16, 0, 0);
}

// ------------------------------------------- W[K][N] f32 -> Wt[N][K] bf16 (x4 fused)
__global__ void transpose_w_kernel(const float* __restrict__ W0, const float* __restrict__ W1,
                                   const float* __restrict__ W2, const float* __restrict__ W3,
                                   unsigned short* __restrict__ T0, unsigned short* __restrict__ T1,
                                   unsigned short* __restrict__ T2, unsigned short* __restrict__ T3){
  __shared__ float tile[32][33];
  const int z = blockIdx.z;
  const float* W = z==0 ? W0 : z==1 ? W1 : z==2 ? W2 : W3;
  unsigned short* Wt = z==0 ? T0 : z==1 ? T1 : z==2 ? T2 : T3;
  int tx = threadIdx.x, ty = threadIdx.y;
  int x0 = blockIdx.x*32, y0 = blockIdx.y*32;
  #pragma unroll
  for (int i=0;i<4;i++)
    tile[ty + i*8][tx] = W[(size_t)(y0 + ty + i*8)*D_MODEL + x0 + tx];
  __syncthreads();
  #pragma unroll
  for (int i=0;i<4;i++)
    Wt[(size_t)(x0 + ty + i*8)*D_MODEL + y0 + tx] = f2b(tile[tx][ty + i*8]);
}

// ---------------------------------------------------------------- proj GEMM
// C[M][N] = A_f32[M][K] * Bt[N][K]^T + bias, 128x128, BK=32, dbuf.
// A staged from f32 via reg+cvt+swizzled ds_write (cvt pass eliminated);
// B staged via global_load_lds with source-swizzle involution.
// LDS[r][u] = G[r][u ^ ((r>>1)&3)]; read chunk crd = lg ^ ((lr>>1)&3).
// mode 0: bf16 row-major out. mode 1: V-transposed Vt[b][h][d][t] bf16.
__device__ __forceinline__ void gemm_body_f32A(const float* __restrict__ A,
                                               const unsigned short* __restrict__ Bt,
                                               const float* __restrict__ bias,
                                               void* __restrict__ Cout, const int mode,
                                               const int m0, const int n0)
{
  constexpr int K = D_MODEL, N = D_MODEL;
  __shared__ unsigned short As[2][128*32];   // 8KB per buf
  __shared__ unsigned short Bs[2][128*32];
  const int t = threadIdx.x, lane = t&63, w = t>>6;
  const int wr = w>>1, wc = w&1, lr = lane&15, lg = lane>>4;
  // B staging (gload16)
  const int srow = lane>>2;
  const int schunk = (lane&3) ^ ((lane>>3)&3);
  // A staging (f32 regs): thread t stages half-row: row ra, chunks 2*half..2*half+1
  const int ra = t>>1, half = t&1;
  const int u0 = (half*2)     ^ ((ra>>1)&3);
  const int u1 = (half*2 + 1) ^ ((ra>>1)&3);
  // read chunk
  const int crd = lg ^ ((lr>>1)&3);
  f32x4 acc[4][4] = {};
  float4 a0,a1,a2,a3;

  auto loadA = [&](int k0){
    const float4* pa = (const float4*)(A + (size_t)(m0+ra)*K + k0 + half*16);
    a0=pa[0]; a1=pa[1]; a2=pa[2]; a3=pa[3];
  };
  auto writeA = [&](int buf){
    u16x8 p0, p1;
    p0[0]=f2b(a0.x); p0[1]=f2b(a0.y); p0[2]=f2b(a0.z); p0[3]=f2b(a0.w);
    p0[4]=f2b(a1.x); p0[5]=f2b(a1.y); p0[6]=f2b(a1.z); p0[7]=f2b(a1.w);
    p1[0]=f2b(a2.x); p1[1]=f2b(a2.y); p1[2]=f2b(a2.z); p1[3]=f2b(a2.w);
    p1[4]=f2b(a3.x); p1[5]=f2b(a3.y); p1[6]=f2b(a3.z); p1[7]=f2b(a3.w);
    *(u16x8*)((char*)As[buf] + ra*64 + u0*16) = p0;
    *(u16x8*)((char*)As[buf] + ra*64 + u1*16) = p1;
  };
  auto stageB = [&](int buf, int k0){
    #pragma unroll
    for (int g=0; g<2; g++){
      int reg = w*2 + g;
      int r = reg*16 + srow;
      gload16(Bt + (size_t)(n0+r)*K + k0 + schunk*8, (char*)Bs[buf] + reg*1024);
    }
  };

  loadA(0); stageB(0, 0); writeA(0);
  __syncthreads();
  int buf = 0;
  for (int ks = 0; ks < 32; ++ks){
    if (ks < 31){ loadA((ks+1)*32); stageB(buf^1, (ks+1)*32); }
    const char* bufA = (const char*)As[buf];
    const char* bufB = (const char*)Bs[buf];
    bf16x8 af[4], bfv[4];
    #pragma unroll
    for (int mi=0;mi<4;mi++){
      int r = wr*64 + mi*16 + lr;
      af[mi] = *(const bf16x8*)(bufA + r*64 + crd*16);
    }
    #pragma unroll
    for (int ni=0;ni<4;ni++){
      int r = wc*64 + ni*16 + lr;
      bfv[ni] = *(const bf16x8*)(bufB + r*64 + crd*16);
    }
    #pragma unroll
    for (int mi=0;mi<4;mi++)
      #pragma unroll
      for (int ni=0;ni<4;ni++)
        acc[mi][ni] = mfma16(af[mi], bfv[ni], acc[mi][ni]);
    if (ks < 31) writeA(buf^1);
    __syncthreads();
    buf ^= 1;
  }

  #pragma unroll
  for (int mi=0;mi<4;mi++){
    #pragma unroll
    for (int ni=0;ni<4;ni++){
      int n = n0 + wc*64 + ni*16 + lr;
      int mbase = m0 + wr*64 + mi*16 + lg*4;
      float bv = bias[n];
      if (mode == 0){
        unsigned short* Cb = (unsigned short*)Cout;
        #pragma unroll
        for (int r=0;r<4;r++) Cb[(size_t)(mbase+r)*N + n] = f2b(acc[mi][ni][r] + bv);
      } else {
        unsigned short* Vt = (unsigned short*)Cout;
        int h = n >> 6, d = n & 63;
        int b = mbase >> 11;
        int tq = mbase & (TT-1);
        u16x4 vv;
        #pragma unroll
        for (int r=0;r<4;r++) vv[r] = f2b(acc[mi][ni][r] + bv);
        *(u16x4*)(Vt + ((size_t)((b*NHEAD + h)*HDIM + d))*TT + tq) = vv;
      }
    }
  }
}

// proj: flat grid 768 = 8 xcd x 8 n x 4 m_inner x 3 z (T1 XCD-locality for A-panels)
__launch_bounds__(256)
__global__ void proj_gemm_kernel(const float* __restrict__ q,
                                 const float* __restrict__ k,
                                 const float* __restrict__ v,
                                 const unsigned short* __restrict__ Wtq,
                                 const unsigned short* __restrict__ Wtk,
                                 const unsigned short* __restrict__ Wtv,
                                 const float* __restrict__ b_q, const float* __restrict__ b_k,
                                 const float* __restrict__ b_v,
                                 unsigned short* __restrict__ Qb, unsigned short* __restrict__ Kb,
                                 unsigned short* __restrict__ Vt)
{
  const int id = blockIdx.x;
  const int xcd = id & 7, r2 = id >> 3;
  const int n = r2 & 7, mz = r2 >> 3;
  const int m = (mz & 3)*8 + xcd, z = mz >> 2;
  const float* A  = z==0 ? q : z==1 ? k : v;
  const unsigned short* Bt = z==0 ? Wtq : z==1 ? Wtk : Wtv;
  const float* bias = z==0 ? b_q : z==1 ? b_k : b_v;
  void* C = z==0 ? (void*)Qb : z==1 ? (void*)Kb : (void*)Vt;
  gemm_body_f32A(A, Bt, bias, C, z==2 ? 1 : 0, m*128, n*128);
}

// out-proj: 64x128 tiles, 512 blocks (2/CU), f32 output, dbuf + gload16
__launch_bounds__(256)
__global__ void out_gemm_kernel(const unsigned short* __restrict__ Ob,
                                const unsigned short* __restrict__ Wto,
                                const float* __restrict__ b_o, float* __restrict__ out)
{
  constexpr int K = D_MODEL, N = D_MODEL;
  __shared__ unsigned short As[2][64*32];    // 4KB per buf
  __shared__ unsigned short Bs[2][128*32];   // 8KB per buf
  const int id = blockIdx.x;
  const int xcd = id & 7, r2 = id >> 3;
  const int n0 = (r2 & 7)*128, m0 = ((r2 >> 3)*8 + xcd)*64;
  const int t = threadIdx.x, lane = t&63, w = t>>6;
  const int wr = w>>1, wc = w&1, lr = lane&15, lg = lane>>4;
  const int srow = lane>>2;
  const int schunk = (lane&3) ^ ((lane>>3)&3);
  const int crd = lg ^ ((lr>>1)&3);
  f32x4 acc[2][4] = {};

  auto stage = [&](int buf, int k0){
    { int r = w*16 + srow;
      gload16(Ob + (size_t)(m0+r)*K + k0 + schunk*8, (char*)As[buf] + w*1024); }
    #pragma unroll
    for (int g=0; g<2; g++){
      int reg = w*2 + g;
      int r = reg*16 + srow;
      gload16(Wto + (size_t)(n0+r)*K + k0 + schunk*8, (char*)Bs[buf] + reg*1024);
    }
  };

  stage(0, 0);
  __syncthreads();
  int buf = 0;
  for (int ks = 0; ks < 32; ++ks){
    if (ks < 31) stage(buf^1, (ks+1)*32);
    const char* bufA = (const char*)As[buf];
    const char* bufB = (const char*)Bs[buf];
    bf16x8 af[2], bfv[4];
    #pragma unroll
    for (int mi=0;mi<2;mi++){
      int r = wr*32 + mi*16 + lr;
      af[mi] = *(const bf16x8*)(bufA + r*64 + crd*16);
    }
    #pragma unroll
    for (int ni=0;ni<4;ni++){
      int r = wc*64 + ni*16 + lr;
      bfv[ni] = *(const bf16x8*)(bufB + r*64 + crd*16);
    }
    #pragma unroll
    for (int mi=0;mi<2;mi++)
      #pragma unroll
      for (int ni=0;ni<4;ni++)
        acc[mi][ni] = mfma16(af[mi], bfv[ni], acc[mi][ni]);
    __syncthreads();
    buf ^= 1;
  }

  #pragma unroll
  for (int mi=0;mi<2;mi++){
    #pragma unroll
    for (int ni=0;ni<4;ni++){
      int n = n0 + wc*64 + ni*16 + lr;
      int mbase = m0 + wr*32 + mi*16 + lg*4;
      float bv = b_o[n];
      #pragma unroll
      for (int r=0;r<4;r++) out[(size_t)(mbase+r)*N + n] = acc[mi][ni][r] + bv;
    }
  }
}

// ------------------------------------------------------- Pass A: column sums
// partialS[qc][bh][col] = sum_{q in 256-chunk qc, q>=col} exp(S[q,col])
__launch_bounds__(256)
__global__ void col_stats_kernel(const unsigned short* __restrict__ Qb,
                                 const unsigned short* __restrict__ Kb,
                                 float* __restrict__ partialS)
{
  __shared__ unsigned short Ks[128*64];      // 16KB static
  __shared__ unsigned short Qs[2][64*64];    // 8KB per buf
  const int t = threadIdx.x, lane = t&63, w = t>>6;
  const int id = blockIdx.x;
  const int bh = id & 31, pair = id >> 5;   // XCD = bh%8 -> per-bh L2 locality
  const int kb_ = pair & 15, qc = pair >> 4;
  const int b = bh >> 4, h = bh & 15;
  const int k0 = kb_ * 128;
  const int lr = lane&15, lg = lane>>4;
  const int osrc = (lane&7) ^ (lane>>3);

  auto stageQ = [&](int buf, int qt){
    #pragma unroll
    for (int g=0; g<2; g++){
      int reg = w*2 + g;
      int r = reg*8 + (lane>>3);
      gload16(Qb + ((size_t)(b*TT + qt + r))*D_MODEL + h*64 + osrc*8,
              (char*)Qs[buf] + reg*1024);
    }
  };

  const int qstart = (k0 > qc*256) ? k0 : qc*256;
  const int qend   = (qc+1)*256;

  #pragma unroll
  for (int g=0; g<4; g++){
    int reg = w*4 + g;
    int r = reg*8 + (lane>>3);
    gload16(Kb + ((size_t)(b*TT + k0 + r))*D_MODEL + h*64 + osrc*8, (char*)Ks + reg*1024);
  }
  if (qstart < qend) stageQ(0, qstart);
  __syncthreads();

  bf16x8 bk[2][2];
  #pragma unroll
  for (int kb=0;kb<2;kb++)
    #pragma unroll
    for (int ks=0;ks<2;ks++){
      int r = w*32 + kb*16 + lr;
      bk[kb][ks] = *(const bf16x8*)((const char*)Ks + r*128 + (((ks*4+lg) ^ (r&7))*16));
    }
  f32x4 sacc[2] = {};
  int buf = 0;
  for (int qt = qstart; qt < qend; qt += 64){
    if (qt + 64 < qend) stageQ(buf^1, qt+64);
    const char* bufQ = (const char*)Qs[buf];
    const bool interior = (qt >= k0 + 128);
    #pragma unroll
    for (int qb=0;qb<4;qb++){
      bf16x8 aq[2];
      #pragma unroll
      for (int ks=0;ks<2;ks++){
        int r = qb*16 + lr;
        aq[ks] = *(const bf16x8*)(bufQ + r*128 + (((ks*4+lg) ^ (r&7))*16));
      }
      f32x4 sf[2] = {};
      #pragma unroll
      for (int ks=0;ks<2;ks++)
        #pragma unroll
        for (int kb=0;kb<2;kb++)
          sf[kb] = mfma16(aq[ks], bk[kb][ks], sf[kb]);
      #pragma unroll
      for (int kb=0;kb<2;kb++){
        int col = k0 + w*32 + kb*16 + lr;
        #pragma unroll
        for (int r=0;r<4;r++){
          float e = __expf(sf[kb][r] * 0.125f);
          if (!interior){
            int qg = qt + qb*16 + lg*4 + r;
            e = (qg >= col) ? e : 0.f;
          }
          sacc[kb][r] += e;
        }
      }
    }
    __syncthreads();
    buf ^= 1;
  }
  #pragma unroll
  for (int kb=0;kb<2;kb++){
    float s = sacc[kb][0] + sacc[kb][1] + sacc[kb][2] + sacc[kb][3];
    s += __shfl_xor(s, 16);
    s += __shfl_xor(s, 32);
    if (lg == 0){
      int col = k0 + w*32 + kb*16 + lr;
      partialS[((size_t)qc*BHN + bh)*TT + col] = s;
    }
  }
}

// --------------------- combine partials + fold 1/sum into V (fused, one launch)
__global__ void col_combine_vscale_kernel(const float* __restrict__ partialS,
                                          unsigned short* __restrict__ Vt){
  const int bh = blockIdx.x >> 3, tc = blockIdx.x & 7;
  const int col = tc*256 + threadIdx.x;
  float s = 0.f;
  #pragma unroll
  for (int qc=0;qc<8;qc++) s += partialS[((size_t)qc*BHN + bh)*TT + col];
  const float inv = 1.0f / s;
  #pragma unroll 8
  for (int d=0; d<HDIM; d++){
    size_t idx = ((size_t)(bh*HDIM + d))*TT + col;
    Vt[idx] = f2b(b2f(Vt[idx]) * inv);
  }
}

// ------------------------------------------------------------- Pass B: output
// O[q,:] = sum_{k<=q} exp(S[q,k]) * V'[k,:]  (V' pre-scaled by invs_k)
// 8 waves x 16 q-rows (QBLK=128); K/V dbuf; swapped QK^T; wave-uniform
// skip of fully-masked diagonal tiles; setprio around MFMA clusters (T5).
__launch_bounds__(512)
__global__ void attn_out_kernel(const unsigned short* __restrict__ Qb,
                                const unsigned short* __restrict__ Kb,
                                const unsigned short* __restrict__ Vt,
                                unsigned short* __restrict__ O)
{
  __shared__ unsigned short Qs[128*64];      // 16KB
  __shared__ unsigned short Ks2[2][64*64];   // 8KB per buf
  __shared__ unsigned short Vs[2][64*64];
  __shared__ unsigned short Ps[128*64];      // 16KB (wave-private 16-row strips)
  const int t = threadIdx.x, lane=t&63, w=t>>6;   // w in 0..7
  const int id = blockIdx.x;
  const int bh = id & 31;                 // XCD = bh%8 -> K/V in one XCD's L2
  const int qi = 15 - (id >> 5);          // heavy blocks first
  const int b = bh>>4, h = bh&15;
  const int q0 = qi*128;
  const int lr = lane&15, lg = lane>>4;
  const int osrc = (lane&7) ^ (lane>>3);

  auto stageKV = [&](int buf, int k0){
    int r = w*8 + (lane>>3);
    gload16(Kb + ((size_t)(b*TT + k0 + r))*D_MODEL + h*64 + osrc*8,
            (char*)Ks2[buf] + w*1024);
    gload16(Vt + ((size_t)(bh*HDIM + r))*TT + k0 + osrc*8,
            (char*)Vs[buf] + w*1024);
  };

  #pragma unroll
  for (int g=0; g<2; g++){
    int reg = w*2 + g;
    int r = reg*8 + (lane>>3);
    gload16(Qb + ((size_t)(b*TT + q0 + r))*D_MODEL + h*64 + osrc*8, (char*)Qs + reg*1024);
  }
  stageKV(0, 0);
  __syncthreads();

  bf16x8 aq[2];
  #pragma unroll
  for (int ks=0;ks<2;ks++){
    int r = w*16 + lr;
    aq[ks] = *(const bf16x8*)((const char*)Qs + r*128 + (((ks*4+lg) ^ (r&7))*16));
  }
  f32x4 oacc[4] = {};
  const int nkt = 2*qi + 2;
  int buf = 0;
  for (int kt=0; kt<nkt; kt++){
    int k0 = kt*64;
    if (kt+1 < nkt) stageKV(buf^1, k0+64);
    // wave-uniform: this wave's q-strip is [q0+w*16, q0+w*16+15]
    const bool active = (k0 <= q0 + w*16 + 15);
    if (active){
      const char* bufK = (const char*)Ks2[buf];
      const char* bufV = (const char*)Vs[buf];
      // S^T = K . Q^T : col = q (lr), row = k
      f32x4 sf[4] = {};
      __builtin_amdgcn_s_setprio(1);
      #pragma unroll
      for (int ks=0;ks<2;ks++)
        #pragma unroll
        for (int kb=0;kb<4;kb++){
          int r = kb*16 + lr;
          bf16x8 bk = *(const bf16x8*)(bufK + r*128 + (((ks*4+lg) ^ (r&7))*16));
          sf[kb] = mfma16(bk, aq[ks], sf[kb]);   // SWAPPED operands
        }
      __builtin_amdgcn_s_setprio(0);
      // P = exp(S); contiguous k-run of 4 -> one b64 LDS write
      const bool boundary = (k0 + 64 > q0 + w*16);
      const int prow = w*16 + lr;
      #pragma unroll
      for (int kb=0;kb<4;kb++){
        u16x4 vv;
        #pragma unroll
        for (int r=0;r<4;r++){
          float pv = __expf(sf[kb][r]*0.125f);
          if (boundary){
            int kg = k0 + kb*16 + lg*4 + r;
            int qg = q0 + prow;
            pv = (qg >= kg) ? pv : 0.f;
          }
          vv[r] = f2b(pv);
        }
        *(u16x4*)((char*)Ps + ((prow*128 + kb*32 + lg*8) ^ ((prow&7)<<4))) = vv;
      }
      // (Ps rows wave-private; in-wave lgkmcnt ordering suffices)
      __builtin_amdgcn_s_setprio(1);
      #pragma unroll
      for (int ks=0;ks<2;ks++){
        bf16x8 pa = *(const bf16x8*)((const char*)Ps + prow*128 + (((ks*4+lg) ^ (prow&7))*16));
        #pragma unroll
        for (int db=0;db<4;db++){
          int r = db*16 + lr;
          bf16x8 bv = *(const bf16x8*)(bufV + r*128 + (((ks*4+lg) ^ (r&7))*16));
          oacc[db] = mfma16(pa, bv, oacc[db]);
        }
      }
      __builtin_amdgcn_s_setprio(0);
    }
    __syncthreads();
    buf ^= 1;
  }
  #pragma unroll
  for (int db=0;db<4;db++){
    int qg = q0 + w*16 + lg*4;
    int d  = db*16 + lr;
    #pragma unroll
    for (int r=0;r<4;r++)
      O[((size_t)(b*TT + qg + r))*D_MODEL + h*64 + d] = f2b(oacc[db][r]);
  }
}

// ---------------------------------------------------------------------- launch
extern "C" void kernel_launch(void* const* d_in, const int* in_sizes, int n_in,
                              void* d_out, int out_size, void* d_ws, size_t ws_size,
                              hipStream_t stream)
{
  (void)in_sizes; (void)n_in; (void)out_size; (void)ws_size;
  const float* q   = (const float*)d_in[0];
  const float* k   = (const float*)d_in[1];
  const float* v   = (const float*)d_in[2];
  const float* w_q = (const float*)d_in[3];
  const float* b_q = (const float*)d_in[4];
  const float* w_k = (const float*)d_in[5];
  const float* b_k = (const float*)d_in[6];
  const float* w_v = (const float*)d_in[7];
  const float* b_v = (const float*)d_in[8];
  const float* w_o = (const float*)d_in[9];
  const float* b_o = (const float*)d_in[10];

  char* p = (char*)d_ws;
  auto carve = [&](size_t bytes)->char* {
    char* r = p; p += (bytes + 255) & ~(size_t)255; return r;
  };
  unsigned short* Wtq = (unsigned short*)carve((size_t)D_MODEL*D_MODEL*2);
  unsigned short* Wtk = (unsigned short*)carve((size_t)D_MODEL*D_MODEL*2);
  unsigned short* Wtv = (unsigned short*)carve((size_t)D_MODEL*D_MODEL*2);
  unsigned short* Wto = (unsigned short*)carve((size_t)D_MODEL*D_MODEL*2);
  unsigned short* Qb  = (unsigned short*)carve((size_t)MM*D_MODEL*2);
  unsigned short* Kb  = (unsigned short*)carve((size_t)MM*D_MODEL*2);
  unsigned short* Vt  = (unsigned short*)carve((size_t)MM*D_MODEL*2);
  unsigned short* Ob  = (unsigned short*)carve((size_t)MM*D_MODEL*2);
  float* partialS = (float*)carve((size_t)8*BHN*TT*4);

  dim3 tgrid(32,32,4), tblk(32,8);
  transpose_w_kernel<<<tgrid, tblk, 0, stream>>>(w_q, w_k, w_v, w_o, Wtq, Wtk, Wtv, Wto);

  proj_gemm_kernel<<<dim3(768), 256, 0, stream>>>(q, k, v, Wtq, Wtk, Wtv,
                                                  b_q, b_k, b_v, Qb, Kb, Vt);

  col_stats_kernel<<<dim3(8*16*BHN), 256, 0, stream>>>(Qb, Kb, partialS);
  col_combine_vscale_kernel<<<dim3(BHN*8), 256, 0, stream>>>(partialS, Vt);

  attn_out_kernel<<<dim3((TT/128)*BHN), 512, 0, stream>>>(Qb, Kb, Vt, Ob);

  out_gemm_kernel<<<dim3(512), 256, 0, stream>>>(Ob, Wto, b_o, (float*)d_out);
}

// Round 9
// 147.281 us; speedup vs baseline: 1.0297x; 1.0297x over previous
//
#include <hip/hip_runtime.h>
#include <hip/hip_bf16.h>
#include <cstdint>
#include <cstddef>

#define D_MODEL 1024
#define NHEAD   16
#define HDIM    64
#define BB      2
#define TT      2048
#define MM      (BB*TT)    // 4096 rows
#define BHN     (BB*NHEAD) // 32

typedef __attribute__((ext_vector_type(8))) __bf16 bf16x8;
typedef __attribute__((ext_vector_type(4))) float  f32x4;
typedef __attribute__((ext_vector_type(8))) unsigned short u16x8;
typedef __attribute__((ext_vector_type(4))) unsigned short u16x4;

__device__ __forceinline__ unsigned short f2b(float f){
  __bf16 b = (__bf16)f;
  return __builtin_bit_cast(unsigned short, b);
}
__device__ __forceinline__ float b2f(unsigned short u){
  unsigned int x = ((unsigned int)u) << 16;
  return __builtin_bit_cast(float, x);
}

__device__ __forceinline__ f32x4 mfma16(bf16x8 a, bf16x8 b, f32x4 c){
  return __builtin_amdgcn_mfma_f32_16x16x32_bf16(a, b, c, 0, 0, 0);
}

// async global->LDS, 16B per lane; LDS dest = wave-uniform base + lane*16.
__device__ __forceinline__ void gload16(const void* g, void* lds){
  __builtin_amdgcn_global_load_lds((const __attribute__((address_space(1))) void*)g,
                                   (__attribute__((address_space(3))) void*)lds, 16, 0, 0);
}

// ------------------------------------------------- cvt f32 -> bf16 (q,k,v fused)
__global__ void cvt_bf16_kernel(const float* __restrict__ q, const float* __restrict__ k,
                                const float* __restrict__ v,
                                unsigned short* __restrict__ Xq, unsigned short* __restrict__ Xk,
                                unsigned short* __restrict__ Xv){
  const int z = blockIdx.y;
  const float* x = z==0 ? q : z==1 ? k : v;
  unsigned short* y = z==0 ? Xq : z==1 ? Xk : Xv;
  size_t i = (size_t)blockIdx.x*blockDim.x + threadIdx.x;
  const float4* p = (const float4*)(x + i*8);
  float4 a = p[0], b = p[1];
  u16x8 o;
  o[0]=f2b(a.x); o[1]=f2b(a.y); o[2]=f2b(a.z); o[3]=f2b(a.w);
  o[4]=f2b(b.x); o[5]=f2b(b.y); o[6]=f2b(b.z); o[7]=f2b(b.w);
  *(u16x8*)(y + i*8) = o;
}

// ------------------------------------------- W[K][N] f32 -> Wt[N][K] bf16 (x4 fused)
__global__ void transpose_w_kernel(const float* __restrict__ W0, const float* __restrict__ W1,
                                   const float* __restrict__ W2, const float* __restrict__ W3,
                                   unsigned short* __restrict__ T0, unsigned short* __restrict__ T1,
                                   unsigned short* __restrict__ T2, unsigned short* __restrict__ T3){
  __shared__ float tile[32][33];
  const int z = blockIdx.z;
  const float* W = z==0 ? W0 : z==1 ? W1 : z==2 ? W2 : W3;
  unsigned short* Wt = z==0 ? T0 : z==1 ? T1 : z==2 ? T2 : T3;
  int tx = threadIdx.x, ty = threadIdx.y;
  int x0 = blockIdx.x*32, y0 = blockIdx.y*32;
  #pragma unroll
  for (int i=0;i<4;i++)
    tile[ty + i*8][tx] = W[(size_t)(y0 + ty + i*8)*D_MODEL + x0 + tx];
  __syncthreads();
  #pragma unroll
  for (int i=0;i<4;i++)
    Wt[(size_t)(x0 + ty + i*8)*D_MODEL + y0 + tx] = f2b(tile[tx][ty + i*8]);
}

// ---------------------------------------------------------------- proj GEMM
// C[M][N] = A[M][K] * Bt[N][K]^T + bias, 128x128, BK=32, TRIPLE-buffered with
// counted vmcnt + raw s_barrier (T4): stage(ks+2) issued at iter ks; end-of-iter
// waits vmcnt(4) (stage ks+1 landed, stage ks+2 still flying). Per-wave vmcnt
// guards that wave's own LDS regions; s_barrier publishes to other waves.
// Ring index: buffers cycle 0,1,2 (bug in R8 — (bi+2)%3 computed wrong for bi=1).
// LDS[r][u] = G[r][u ^ ((r>>1)&3)]; read chunk crd = lg ^ ((lr>>1)&3).
// mode 0: bf16 row-major out. mode 1: V-transposed Vt[b][h][d][t] bf16.
__device__ __forceinline__ void gemm_body(const unsigned short* __restrict__ A,
                                          const unsigned short* __restrict__ Bt,
                                          const float* __restrict__ bias,
                                          void* __restrict__ Cout, const int mode,
                                          const int m0, const int n0)
{
  constexpr int K = D_MODEL, N = D_MODEL;
  __shared__ unsigned short As[3][128*32];   // 8KB per buf
  __shared__ unsigned short Bs[3][128*32];   // 48KB total -> 3 blocks/CU
  const int t = threadIdx.x, lane = t&63, w = t>>6;
  const int wr = w>>1, wc = w&1, lr = lane&15, lg = lane>>4;
  const int srow = lane>>2;                      // row within 16-row region
  const int schunk = (lane&3) ^ ((lane>>3)&3);   // involution source chunk
  const int crd = lg ^ ((lr>>1)&3);              // read chunk (lane-const)
  f32x4 acc[4][4] = {};

  auto stage = [&](int buf, int ks){
    int k0 = ks*32;
    #pragma unroll
    for (int g=0; g<2; g++){
      int reg = w*2 + g;                         // 1KB region = 16 rows x 64B
      int r = reg*16 + srow;
      gload16(A  + (size_t)(m0+r)*K + k0 + schunk*8, (char*)As[buf] + reg*1024);
      gload16(Bt + (size_t)(n0+r)*K + k0 + schunk*8, (char*)Bs[buf] + reg*1024);
    }
  };

  stage(0, 0);                                   // 4 vmem ops/thread
  stage(1, 1);                                   // 8 outstanding
  asm volatile("s_waitcnt vmcnt(4)" ::: "memory");  // buf0 landed
  asm volatile("s_barrier" ::: "memory");

  int bi = 0;
  for (int ks = 0; ks < 32; ++ks){
    if (ks + 2 < 32){
      int nb = bi + 2; if (nb >= 3) nb -= 3;     // FIXED ring index
      stage(nb, ks+2);
    }
    const char* bufA = (const char*)As[bi];
    const char* bufB = (const char*)Bs[bi];
    bf16x8 af[4], bfv[4];
    #pragma unroll
    for (int mi=0;mi<4;mi++){
      int r = wr*64 + mi*16 + lr;
      af[mi] = *(const bf16x8*)(bufA + r*64 + crd*16);
    }
    #pragma unroll
    for (int ni=0;ni<4;ni++){
      int r = wc*64 + ni*16 + lr;
      bfv[ni] = *(const bf16x8*)(bufB + r*64 + crd*16);
    }
    #pragma unroll
    for (int mi=0;mi<4;mi++)
      #pragma unroll
      for (int ni=0;ni<4;ni++)
        acc[mi][ni] = mfma16(af[mi], bfv[ni], acc[mi][ni]);
    if (ks < 30) asm volatile("s_waitcnt vmcnt(4)" ::: "memory");
    else         asm volatile("s_waitcnt vmcnt(0)" ::: "memory");
    asm volatile("s_barrier" ::: "memory");
    bi = (bi == 2) ? 0 : bi + 1;
  }

  #pragma unroll
  for (int mi=0;mi<4;mi++){
    #pragma unroll
    for (int ni=0;ni<4;ni++){
      int n = n0 + wc*64 + ni*16 + lr;
      int mbase = m0 + wr*64 + mi*16 + lg*4;
      float bv = bias[n];
      if (mode == 0){
        unsigned short* Cb = (unsigned short*)Cout;
        #pragma unroll
        for (int r=0;r<4;r++) Cb[(size_t)(mbase+r)*N + n] = f2b(acc[mi][ni][r] + bv);
      } else {
        unsigned short* Vt = (unsigned short*)Cout;
        int h = n >> 6, d = n & 63;
        int b = mbase >> 11;
        int tq = mbase & (TT-1);
        u16x4 vv;
        #pragma unroll
        for (int r=0;r<4;r++) vv[r] = f2b(acc[mi][ni][r] + bv);
        *(u16x4*)(Vt + ((size_t)((b*NHEAD + h)*HDIM + d))*TT + tq) = vv;
      }
    }
  }
}

// proj: flat grid 768 = 8 xcd x 8 n x 4 m_inner x 3 z (T1 XCD-locality for A-panels)
__launch_bounds__(256)
__global__ void proj_gemm_kernel(const unsigned short* __restrict__ Xq,
                                 const unsigned short* __restrict__ Xk,
                                 const unsigned short* __restrict__ Xv,
                                 const unsigned short* __restrict__ Wtq,
                                 const unsigned short* __restrict__ Wtk,
                                 const unsigned short* __restrict__ Wtv,
                                 const float* __restrict__ b_q, const float* __restrict__ b_k,
                                 const float* __restrict__ b_v,
                                 unsigned short* __restrict__ Qb, unsigned short* __restrict__ Kb,
                                 unsigned short* __restrict__ Vt)
{
  const int id = blockIdx.x;
  const int xcd = id & 7, r2 = id >> 3;
  const int n = r2 & 7, mz = r2 >> 3;
  const int m = (mz & 3)*8 + xcd, z = mz >> 2;
  const unsigned short* A  = z==0 ? Xq : z==1 ? Xk : Xv;
  const unsigned short* Bt = z==0 ? Wtq : z==1 ? Wtk : Wtv;
  const float* bias = z==0 ? b_q : z==1 ? b_k : b_v;
  void* C = z==0 ? (void*)Qb : z==1 ? (void*)Kb : (void*)Vt;
  gemm_body(A, Bt, bias, C, z==2 ? 1 : 0, m*128, n*128);
}

// out-proj: 64x128 tiles, 512 blocks (2/CU), f32 output, dbuf + gload16
__launch_bounds__(256)
__global__ void out_gemm_kernel(const unsigned short* __restrict__ Ob,
                                const unsigned short* __restrict__ Wto,
                                const float* __restrict__ b_o, float* __restrict__ out)
{
  constexpr int K = D_MODEL, N = D_MODEL;
  __shared__ unsigned short As[2][64*32];    // 4KB per buf
  __shared__ unsigned short Bs[2][128*32];   // 8KB per buf
  const int id = blockIdx.x;
  const int xcd = id & 7, r2 = id >> 3;
  const int n0 = (r2 & 7)*128, m0 = ((r2 >> 3)*8 + xcd)*64;
  const int t = threadIdx.x, lane = t&63, w = t>>6;
  const int wr = w>>1, wc = w&1, lr = lane&15, lg = lane>>4;
  const int srow = lane>>2;
  const int schunk = (lane&3) ^ ((lane>>3)&3);
  const int crd = lg ^ ((lr>>1)&3);
  f32x4 acc[2][4] = {};

  auto stage = [&](int buf, int k0){
    { int r = w*16 + srow;
      gload16(Ob + (size_t)(m0+r)*K + k0 + schunk*8, (char*)As[buf] + w*1024); }
    #pragma unroll
    for (int g=0; g<2; g++){
      int reg = w*2 + g;
      int r = reg*16 + srow;
      gload16(Wto + (size_t)(n0+r)*K + k0 + schunk*8, (char*)Bs[buf] + reg*1024);
    }
  };

  stage(0, 0);
  __syncthreads();
  int buf = 0;
  for (int ks = 0; ks < 32; ++ks){
    if (ks < 31) stage(buf^1, (ks+1)*32);
    const char* bufA = (const char*)As[buf];
    const char* bufB = (const char*)Bs[buf];
    bf16x8 af[2], bfv[4];
    #pragma unroll
    for (int mi=0;mi<2;mi++){
      int r = wr*32 + mi*16 + lr;
      af[mi] = *(const bf16x8*)(bufA + r*64 + crd*16);
    }
    #pragma unroll
    for (int ni=0;ni<4;ni++){
      int r = wc*64 + ni*16 + lr;
      bfv[ni] = *(const bf16x8*)(bufB + r*64 + crd*16);
    }
    #pragma unroll
    for (int mi=0;mi<2;mi++)
      #pragma unroll
      for (int ni=0;ni<4;ni++)
        acc[mi][ni] = mfma16(af[mi], bfv[ni], acc[mi][ni]);
    __syncthreads();
    buf ^= 1;
  }

  #pragma unroll
  for (int mi=0;mi<2;mi++){
    #pragma unroll
    for (int ni=0;ni<4;ni++){
      int n = n0 + wc*64 + ni*16 + lr;
      int mbase = m0 + wr*32 + mi*16 + lg*4;
      float bv = b_o[n];
      #pragma unroll
      for (int r=0;r<4;r++) out[(size_t)(mbase+r)*N + n] = acc[mi][ni][r] + bv;
    }
  }
}

// ------------------------------------------------------- Pass A: column sums
// partialS[qc][bh][col] = sum_{q in 256-chunk qc, q>=col} exp(S[q,col])
__launch_bounds__(256)
__global__ void col_stats_kernel(const unsigned short* __restrict__ Qb,
                                 const unsigned short* __restrict__ Kb,
                                 float* __restrict__ partialS)
{
  __shared__ unsigned short Ks[128*64];      // 16KB static
  __shared__ unsigned short Qs[2][64*64];    // 8KB per buf
  const int t = threadIdx.x, lane = t&63, w = t>>6;
  const int id = blockIdx.x;
  const int bh = id & 31, pair = id >> 5;   // XCD = bh%8 -> per-bh L2 locality
  const int kb_ = pair & 15, qc = pair >> 4;
  const int b = bh >> 4, h = bh & 15;
  const int k0 = kb_ * 128;
  const int lr = lane&15, lg = lane>>4;
  const int osrc = (lane&7) ^ (lane>>3);

  auto stageQ = [&](int buf, int qt){
    #pragma unroll
    for (int g=0; g<2; g++){
      int reg = w*2 + g;
      int r = reg*8 + (lane>>3);
      gload16(Qb + ((size_t)(b*TT + qt + r))*D_MODEL + h*64 + osrc*8,
              (char*)Qs[buf] + reg*1024);
    }
  };

  const int qstart = (k0 > qc*256) ? k0 : qc*256;
  const int qend   = (qc+1)*256;

  #pragma unroll
  for (int g=0; g<4; g++){
    int reg = w*4 + g;
    int r = reg*8 + (lane>>3);
    gload16(Kb + ((size_t)(b*TT + k0 + r))*D_MODEL + h*64 + osrc*8, (char*)Ks + reg*1024);
  }
  if (qstart < qend) stageQ(0, qstart);
  __syncthreads();

  bf16x8 bk[2][2];
  #pragma unroll
  for (int kb=0;kb<2;kb++)
    #pragma unroll
    for (int ks=0;ks<2;ks++){
      int r = w*32 + kb*16 + lr;
      bk[kb][ks] = *(const bf16x8*)((const char*)Ks + r*128 + (((ks*4+lg) ^ (r&7))*16));
    }
  f32x4 sacc[2] = {};
  int buf = 0;
  for (int qt = qstart; qt < qend; qt += 64){
    if (qt + 64 < qend) stageQ(buf^1, qt+64);
    const char* bufQ = (const char*)Qs[buf];
    const bool interior = (qt >= k0 + 128);
    #pragma unroll
    for (int qb=0;qb<4;qb++){
      bf16x8 aq[2];
      #pragma unroll
      for (int ks=0;ks<2;ks++){
        int r = qb*16 + lr;
        aq[ks] = *(const bf16x8*)(bufQ + r*128 + (((ks*4+lg) ^ (r&7))*16));
      }
      f32x4 sf[2] = {};
      #pragma unroll
      for (int ks=0;ks<2;ks++)
        #pragma unroll
        for (int kb=0;kb<2;kb++)
          sf[kb] = mfma16(aq[ks], bk[kb][ks], sf[kb]);
      #pragma unroll
      for (int kb=0;kb<2;kb++){
        int col = k0 + w*32 + kb*16 + lr;
        #pragma unroll
        for (int r=0;r<4;r++){
          float e = __expf(sf[kb][r] * 0.125f);
          if (!interior){
            int qg = qt + qb*16 + lg*4 + r;
            e = (qg >= col) ? e : 0.f;
          }
          sacc[kb][r] += e;
        }
      }
    }
    __syncthreads();
    buf ^= 1;
  }
  #pragma unroll
  for (int kb=0;kb<2;kb++){
    float s = sacc[kb][0] + sacc[kb][1] + sacc[kb][2] + sacc[kb][3];
    s += __shfl_xor(s, 16);
    s += __shfl_xor(s, 32);
    if (lg == 0){
      int col = k0 + w*32 + kb*16 + lr;
      partialS[((size_t)qc*BHN + bh)*TT + col] = s;
    }
  }
}

// --------------------- combine partials + fold 1/sum into V (fused, one launch)
__global__ void col_combine_vscale_kernel(const float* __restrict__ partialS,
                                          unsigned short* __restrict__ Vt){
  const int bh = blockIdx.x >> 3, tc = blockIdx.x & 7;
  const int col = tc*256 + threadIdx.x;
  float s = 0.f;
  #pragma unroll
  for (int qc=0;qc<8;qc++) s += partialS[((size_t)qc*BHN + bh)*TT + col];
  const float inv = 1.0f / s;
  #pragma unroll 8
  for (int d=0; d<HDIM; d++){
    size_t idx = ((size_t)(bh*HDIM + d))*TT + col;
    Vt[idx] = f2b(b2f(Vt[idx]) * inv);
  }
}

// ------------------------------------------------------------- Pass B: output
// O[q,:] = sum_{k<=q} exp(S[q,k]) * V'[k,:]  (V' pre-scaled by invs_k)
// 8 waves x 16 q-rows (QBLK=128); K/V dbuf; swapped QK^T; wave-uniform
// skip of fully-masked diagonal tiles; setprio around MFMA clusters (T5).
__launch_bounds__(512)
__global__ void attn_out_kernel(const unsigned short* __restrict__ Qb,
                                const unsigned short* __restrict__ Kb,
                                const unsigned short* __restrict__ Vt,
                                unsigned short* __restrict__ O)
{
  __shared__ unsigned short Qs[128*64];      // 16KB
  __shared__ unsigned short Ks2[2][64*64];   // 8KB per buf
  __shared__ unsigned short Vs[2][64*64];
  __shared__ unsigned short Ps[128*64];      // 16KB (wave-private 16-row strips)
  const int t = threadIdx.x, lane=t&63, w=t>>6;   // w in 0..7
  const int id = blockIdx.x;
  const int bh = id & 31;                 // XCD = bh%8 -> K/V in one XCD's L2
  const int qi = 15 - (id >> 5);          // heavy blocks first
  const int b = bh>>4, h = bh&15;
  const int q0 = qi*128;
  const int lr = lane&15, lg = lane>>4;
  const int osrc = (lane&7) ^ (lane>>3);

  auto stageKV = [&](int buf, int k0){
    int r = w*8 + (lane>>3);
    gload16(Kb + ((size_t)(b*TT + k0 + r))*D_MODEL + h*64 + osrc*8,
            (char*)Ks2[buf] + w*1024);
    gload16(Vt + ((size_t)(bh*HDIM + r))*TT + k0 + osrc*8,
            (char*)Vs[buf] + w*1024);
  };

  #pragma unroll
  for (int g=0; g<2; g++){
    int reg = w*2 + g;
    int r = reg*8 + (lane>>3);
    gload16(Qb + ((size_t)(b*TT + q0 + r))*D_MODEL + h*64 + osrc*8, (char*)Qs + reg*1024);
  }
  stageKV(0, 0);
  __syncthreads();

  bf16x8 aq[2];
  #pragma unroll
  for (int ks=0;ks<2;ks++){
    int r = w*16 + lr;
    aq[ks] = *(const bf16x8*)((const char*)Qs + r*128 + (((ks*4+lg) ^ (r&7))*16));
  }
  f32x4 oacc[4] = {};
  const int nkt = 2*qi + 2;
  int buf = 0;
  for (int kt=0; kt<nkt; kt++){
    int k0 = kt*64;
    if (kt+1 < nkt) stageKV(buf^1, k0+64);
    // wave-uniform: this wave's q-strip is [q0+w*16, q0+w*16+15]
    const bool active = (k0 <= q0 + w*16 + 15);
    if (active){
      const char* bufK = (const char*)Ks2[buf];
      const char* bufV = (const char*)Vs[buf];
      // S^T = K . Q^T : col = q (lr), row = k
      f32x4 sf[4] = {};
      __builtin_amdgcn_s_setprio(1);
      #pragma unroll
      for (int ks=0;ks<2;ks++)
        #pragma unroll
        for (int kb=0;kb<4;kb++){
          int r = kb*16 + lr;
          bf16x8 bk = *(const bf16x8*)(bufK + r*128 + (((ks*4+lg) ^ (r&7))*16));
          sf[kb] = mfma16(bk, aq[ks], sf[kb]);   // SWAPPED operands
        }
      __builtin_amdgcn_s_setprio(0);
      // P = exp(S); contiguous k-run of 4 -> one b64 LDS write
      const bool boundary = (k0 + 64 > q0 + w*16);
      const int prow = w*16 + lr;
      #pragma unroll
      for (int kb=0;kb<4;kb++){
        u16x4 vv;
        #pragma unroll
        for (int r=0;r<4;r++){
          float pv = __expf(sf[kb][r]*0.125f);
          if (boundary){
            int kg = k0 + kb*16 + lg*4 + r;
            int qg = q0 + prow;
            pv = (qg >= kg) ? pv : 0.f;
          }
          vv[r] = f2b(pv);
        }
        *(u16x4*)((char*)Ps + ((prow*128 + kb*32 + lg*8) ^ ((prow&7)<<4))) = vv;
      }
      // (Ps rows wave-private; in-wave lgkmcnt ordering suffices)
      __builtin_amdgcn_s_setprio(1);
      #pragma unroll
      for (int ks=0;ks<2;ks++){
        bf16x8 pa = *(const bf16x8*)((const char*)Ps + prow*128 + (((ks*4+lg) ^ (prow&7))*16));
        #pragma unroll
        for (int db=0;db<4;db++){
          int r = db*16 + lr;
          bf16x8 bv = *(const bf16x8*)(bufV + r*128 + (((ks*4+lg) ^ (r&7))*16));
          oacc[db] = mfma16(pa, bv, oacc[db]);
        }
      }
      __builtin_amdgcn_s_setprio(0);
    }
    __syncthreads();
    buf ^= 1;
  }
  #pragma unroll
  for (int db=0;db<4;db++){
    int qg = q0 + w*16 + lg*4;
    int d  = db*16 + lr;
    #pragma unroll
    for (int r=0;r<4;r++)
      O[((size_t)(b*TT + qg + r))*D_MODEL + h*64 + d] = f2b(oacc[db][r]);
  }
}

// ---------------------------------------------------------------------- launch
extern "C" void kernel_launch(void* const* d_in, const int* in_sizes, int n_in,
                              void* d_out, int out_size, void* d_ws, size_t ws_size,
                              hipStream_t stream)
{
  (void)in_sizes; (void)n_in; (void)out_size; (void)ws_size;
  const float* q   = (const float*)d_in[0];
  const float* k   = (const float*)d_in[1];
  const float* v   = (const float*)d_in[2];
  const float* w_q = (const float*)d_in[3];
  const float* b_q = (const float*)d_in[4];
  const float* w_k = (const float*)d_in[5];
  const float* b_k = (const float*)d_in[6];
  const float* w_v = (const float*)d_in[7];
  const float* b_v = (const float*)d_in[8];
  const float* w_o = (const float*)d_in[9];
  const float* b_o = (const float*)d_in[10];

  char* p = (char*)d_ws;
  auto carve = [&](size_t bytes)->char* {
    char* r = p; p += (bytes + 255) & ~(size_t)255; return r;
  };
  unsigned short* Xq  = (unsigned short*)carve((size_t)MM*D_MODEL*2);
  unsigned short* Xk  = (unsigned short*)carve((size_t)MM*D_MODEL*2);
  unsigned short* Xv  = (unsigned short*)carve((size_t)MM*D_MODEL*2);
  unsigned short* Wtq = (unsigned short*)carve((size_t)D_MODEL*D_MODEL*2);
  unsigned short* Wtk = (unsigned short*)carve((size_t)D_MODEL*D_MODEL*2);
  unsigned short* Wtv = (unsigned short*)carve((size_t)D_MODEL*D_MODEL*2);
  unsigned short* Wto = (unsigned short*)carve((size_t)D_MODEL*D_MODEL*2);
  unsigned short* Qb  = (unsigned short*)carve((size_t)MM*D_MODEL*2);
  unsigned short* Kb  = (unsigned short*)carve((size_t)MM*D_MODEL*2);
  unsigned short* Vt  = (unsigned short*)carve((size_t)MM*D_MODEL*2);
  unsigned short* Ob  = (unsigned short*)carve((size_t)MM*D_MODEL*2);
  float* partialS = (float*)carve((size_t)8*BHN*TT*4);

  cvt_bf16_kernel<<<dim3((MM*D_MODEL/8)/256, 3), 256, 0, stream>>>(q, k, v, Xq, Xk, Xv);

  dim3 tgrid(32,32,4), tblk(32,8);
  transpose_w_kernel<<<tgrid, tblk, 0, stream>>>(w_q, w_k, w_v, w_o, Wtq, Wtk, Wtv, Wto);

  proj_gemm_kernel<<<dim3(768), 256, 0, stream>>>(Xq, Xk, Xv, Wtq, Wtk, Wtv,
                                                  b_q, b_k, b_v, Qb, Kb, Vt);

  col_stats_kernel<<<dim3(8*16*BHN), 256, 0, stream>>>(Qb, Kb, partialS);
  col_combine_vscale_kernel<<<dim3(BHN*8), 256, 0, stream>>>(partialS, Vt);

  attn_out_kernel<<<dim3((TT/128)*BHN), 512, 0, stream>>>(Qb, Kb, Vt, Ob);

  out_gemm_kernel<<<dim3(512), 256, 0, stream>>>(Ob, Wto, b_o, (float*)d_out);
}

// Round 10
// 142.569 us; speedup vs baseline: 1.0638x; 1.0330x over previous
//
#include <hip/hip_runtime.h>
#include <hip/hip_bf16.h>
#include <cstdint>
#include <cstddef>

#define D_MODEL 1024
#define NHEAD   16
#define HDIM    64
#define BB      2
#define TT      2048
#define MM      (BB*TT)    // 4096 rows
#define BHN     (BB*NHEAD) // 32

typedef __attribute__((ext_vector_type(8))) __bf16 bf16x8;
typedef __attribute__((ext_vector_type(4))) float  f32x4;
typedef __attribute__((ext_vector_type(8))) unsigned short u16x8;
typedef __attribute__((ext_vector_type(4))) unsigned short u16x4;

__device__ __forceinline__ unsigned short f2b(float f){
  __bf16 b = (__bf16)f;
  return __builtin_bit_cast(unsigned short, b);
}

__device__ __forceinline__ f32x4 mfma16(bf16x8 a, bf16x8 b, f32x4 c){
  return __builtin_amdgcn_mfma_f32_16x16x32_bf16(a, b, c, 0, 0, 0);
}

// async global->LDS, 16B per lane; LDS dest = wave-uniform base + lane*16.
__device__ __forceinline__ void gload16(const void* g, void* lds){
  __builtin_amdgcn_global_load_lds((const __attribute__((address_space(1))) void*)g,
                                   (__attribute__((address_space(3))) void*)lds, 16, 0, 0);
}

// -------------------- fused preprocessing: cvt q/k/v (blocks 0..6143) +
// -------------------- transpose 4 weights (blocks 6144..10239)
__global__ void pre_kernel(const float* __restrict__ q, const float* __restrict__ k,
                           const float* __restrict__ v,
                           unsigned short* __restrict__ Xq, unsigned short* __restrict__ Xk,
                           unsigned short* __restrict__ Xv,
                           const float* __restrict__ W0, const float* __restrict__ W1,
                           const float* __restrict__ W2, const float* __restrict__ W3,
                           unsigned short* __restrict__ T0, unsigned short* __restrict__ T1,
                           unsigned short* __restrict__ T2, unsigned short* __restrict__ T3)
{
  __shared__ float tile[32][33];
  const int id = blockIdx.x;
  if (id < 6144){
    const int z = id / 2048, ib = id - z*2048;
    const float* x = z==0 ? q : z==1 ? k : v;
    unsigned short* y = z==0 ? Xq : z==1 ? Xk : Xv;
    size_t i = (size_t)ib*256 + threadIdx.x;
    const float4* p = (const float4*)(x + i*8);
    float4 a = p[0], b = p[1];
    u16x8 o;
    o[0]=f2b(a.x); o[1]=f2b(a.y); o[2]=f2b(a.z); o[3]=f2b(a.w);
    o[4]=f2b(b.x); o[5]=f2b(b.y); o[6]=f2b(b.z); o[7]=f2b(b.w);
    *(u16x8*)(y + i*8) = o;
  } else {
    const int tid = id - 6144;
    const int z = tid >> 10;
    const int by = (tid >> 5) & 31, bx = tid & 31;
    const float* W = z==0 ? W0 : z==1 ? W1 : z==2 ? W2 : W3;
    unsigned short* Wt = z==0 ? T0 : z==1 ? T1 : z==2 ? T2 : T3;
    const int tx = threadIdx.x & 31, ty = threadIdx.x >> 5;
    const int x0 = bx*32, y0 = by*32;
    #pragma unroll
    for (int i=0;i<4;i++)
      tile[ty + i*8][tx] = W[(size_t)(y0 + ty + i*8)*D_MODEL + x0 + tx];
    __syncthreads();
    #pragma unroll
    for (int i=0;i<4;i++)
      Wt[(size_t)(x0 + ty + i*8)*D_MODEL + y0 + tx] = f2b(tile[tx][ty + i*8]);
  }
}

// ---------------------------------------------------------------- proj GEMM
// C[M][N] = A[M][K] * Bt[N][K]^T + bias, 128x128, BK=32, double-buffered
// (R6 structure — best measured; counted-vmcnt ring gave no gain).
// LDS[r][u] = G[r][u ^ ((r>>1)&3)]; read chunk crd = lg ^ ((lr>>1)&3).
// mode 0: bf16 row-major out. mode 1: V-transposed Vt[b][h][d][t] bf16.
__device__ __forceinline__ void gemm_body(const unsigned short* __restrict__ A,
                                          const unsigned short* __restrict__ Bt,
                                          const float* __restrict__ bias,
                                          void* __restrict__ Cout, const int mode,
                                          const int m0, const int n0)
{
  constexpr int K = D_MODEL, N = D_MODEL;
  __shared__ unsigned short As[2][128*32];   // 8KB per buf
  __shared__ unsigned short Bs[2][128*32];
  const int t = threadIdx.x, lane = t&63, w = t>>6;
  const int wr = w>>1, wc = w&1, lr = lane&15, lg = lane>>4;
  const int srow = lane>>2;                      // row within 16-row region
  const int schunk = (lane&3) ^ ((lane>>3)&3);   // involution source chunk
  const int crd = lg ^ ((lr>>1)&3);              // read chunk (lane-const)
  f32x4 acc[4][4] = {};

  auto stage = [&](int buf, int k0){
    #pragma unroll
    for (int g=0; g<2; g++){
      int reg = w*2 + g;                         // 1KB region = 16 rows x 64B
      int r = reg*16 + srow;
      gload16(A  + (size_t)(m0+r)*K + k0 + schunk*8, (char*)As[buf] + reg*1024);
      gload16(Bt + (size_t)(n0+r)*K + k0 + schunk*8, (char*)Bs[buf] + reg*1024);
    }
  };

  stage(0, 0);
  __syncthreads();
  int buf = 0;
  for (int ks = 0; ks < 32; ++ks){
    if (ks < 31) stage(buf^1, (ks+1)*32);
    const char* bufA = (const char*)As[buf];
    const char* bufB = (const char*)Bs[buf];
    bf16x8 af[4], bfv[4];
    #pragma unroll
    for (int mi=0;mi<4;mi++){
      int r = wr*64 + mi*16 + lr;
      af[mi] = *(const bf16x8*)(bufA + r*64 + crd*16);
    }
    #pragma unroll
    for (int ni=0;ni<4;ni++){
      int r = wc*64 + ni*16 + lr;
      bfv[ni] = *(const bf16x8*)(bufB + r*64 + crd*16);
    }
    #pragma unroll
    for (int mi=0;mi<4;mi++)
      #pragma unroll
      for (int ni=0;ni<4;ni++)
        acc[mi][ni] = mfma16(af[mi], bfv[ni], acc[mi][ni]);
    __syncthreads();
    buf ^= 1;
  }

  #pragma unroll
  for (int mi=0;mi<4;mi++){
    #pragma unroll
    for (int ni=0;ni<4;ni++){
      int n = n0 + wc*64 + ni*16 + lr;
      int mbase = m0 + wr*64 + mi*16 + lg*4;
      float bv = bias[n];
      if (mode == 0){
        unsigned short* Cb = (unsigned short*)Cout;
        #pragma unroll
        for (int r=0;r<4;r++) Cb[(size_t)(mbase+r)*N + n] = f2b(acc[mi][ni][r] + bv);
      } else {
        unsigned short* Vt = (unsigned short*)Cout;
        int h = n >> 6, d = n & 63;
        int b = mbase >> 11;
        int tq = mbase & (TT-1);
        u16x4 vv;
        #pragma unroll
        for (int r=0;r<4;r++) vv[r] = f2b(acc[mi][ni][r] + bv);
        *(u16x4*)(Vt + ((size_t)((b*NHEAD + h)*HDIM + d))*TT + tq) = vv;
      }
    }
  }
}

// proj: flat grid 768 = 8 xcd x 8 n x 4 m_inner x 3 z (T1 XCD-locality for A-panels)
__launch_bounds__(256)
__global__ void proj_gemm_kernel(const unsigned short* __restrict__ Xq,
                                 const unsigned short* __restrict__ Xk,
                                 const unsigned short* __restrict__ Xv,
                                 const unsigned short* __restrict__ Wtq,
                                 const unsigned short* __restrict__ Wtk,
                                 const unsigned short* __restrict__ Wtv,
                                 const float* __restrict__ b_q, const float* __restrict__ b_k,
                                 const float* __restrict__ b_v,
                                 unsigned short* __restrict__ Qb, unsigned short* __restrict__ Kb,
                                 unsigned short* __restrict__ Vt)
{
  const int id = blockIdx.x;
  const int xcd = id & 7, r2 = id >> 3;
  const int n = r2 & 7, mz = r2 >> 3;
  const int m = (mz & 3)*8 + xcd, z = mz >> 2;
  const unsigned short* A  = z==0 ? Xq : z==1 ? Xk : Xv;
  const unsigned short* Bt = z==0 ? Wtq : z==1 ? Wtk : Wtv;
  const float* bias = z==0 ? b_q : z==1 ? b_k : b_v;
  void* C = z==0 ? (void*)Qb : z==1 ? (void*)Kb : (void*)Vt;
  gemm_body(A, Bt, bias, C, z==2 ? 1 : 0, m*128, n*128);
}

// out-proj: 64x128 tiles, 512 blocks (2/CU), f32 output, dbuf + gload16
__launch_bounds__(256)
__global__ void out_gemm_kernel(const unsigned short* __restrict__ Ob,
                                const unsigned short* __restrict__ Wto,
                                const float* __restrict__ b_o, float* __restrict__ out)
{
  constexpr int K = D_MODEL, N = D_MODEL;
  __shared__ unsigned short As[2][64*32];    // 4KB per buf
  __shared__ unsigned short Bs[2][128*32];   // 8KB per buf
  const int id = blockIdx.x;
  const int xcd = id & 7, r2 = id >> 3;
  const int n0 = (r2 & 7)*128, m0 = ((r2 >> 3)*8 + xcd)*64;
  const int t = threadIdx.x, lane = t&63, w = t>>6;
  const int wr = w>>1, wc = w&1, lr = lane&15, lg = lane>>4;
  const int srow = lane>>2;
  const int schunk = (lane&3) ^ ((lane>>3)&3);
  const int crd = lg ^ ((lr>>1)&3);
  f32x4 acc[2][4] = {};

  auto stage = [&](int buf, int k0){
    { int r = w*16 + srow;
      gload16(Ob + (size_t)(m0+r)*K + k0 + schunk*8, (char*)As[buf] + w*1024); }
    #pragma unroll
    for (int g=0; g<2; g++){
      int reg = w*2 + g;
      int r = reg*16 + srow;
      gload16(Wto + (size_t)(n0+r)*K + k0 + schunk*8, (char*)Bs[buf] + reg*1024);
    }
  };

  stage(0, 0);
  __syncthreads();
  int buf = 0;
  for (int ks = 0; ks < 32; ++ks){
    if (ks < 31) stage(buf^1, (ks+1)*32);
    const char* bufA = (const char*)As[buf];
    const char* bufB = (const char*)Bs[buf];
    bf16x8 af[2], bfv[4];
    #pragma unroll
    for (int mi=0;mi<2;mi++){
      int r = wr*32 + mi*16 + lr;
      af[mi] = *(const bf16x8*)(bufA + r*64 + crd*16);
    }
    #pragma unroll
    for (int ni=0;ni<4;ni++){
      int r = wc*64 + ni*16 + lr;
      bfv[ni] = *(const bf16x8*)(bufB + r*64 + crd*16);
    }
    #pragma unroll
    for (int mi=0;mi<2;mi++)
      #pragma unroll
      for (int ni=0;ni<4;ni++)
        acc[mi][ni] = mfma16(af[mi], bfv[ni], acc[mi][ni]);
    __syncthreads();
    buf ^= 1;
  }

  #pragma unroll
  for (int mi=0;mi<2;mi++){
    #pragma unroll
    for (int ni=0;ni<4;ni++){
      int n = n0 + wc*64 + ni*16 + lr;
      int mbase = m0 + wr*32 + mi*16 + lg*4;
      float bv = b_o[n];
      #pragma unroll
      for (int r=0;r<4;r++) out[(size_t)(mbase+r)*N + n] = acc[mi][ni][r] + bv;
    }
  }
}

// ------------------------------------------------------- Pass A: column sums
// partialS[qc][bh][col] = sum_{q in 256-chunk qc, q>=col} exp(S[q,col])
__launch_bounds__(256)
__global__ void col_stats_kernel(const unsigned short* __restrict__ Qb,
                                 const unsigned short* __restrict__ Kb,
                                 float* __restrict__ partialS)
{
  __shared__ unsigned short Ks[128*64];      // 16KB static
  __shared__ unsigned short Qs[2][64*64];    // 8KB per buf
  const int t = threadIdx.x, lane = t&63, w = t>>6;
  const int id = blockIdx.x;
  const int bh = id & 31, pair = id >> 5;   // XCD = bh%8 -> per-bh L2 locality
  const int kb_ = pair & 15, qc = pair >> 4;
  const int b = bh >> 4, h = bh & 15;
  const int k0 = kb_ * 128;
  const int lr = lane&15, lg = lane>>4;
  const int osrc = (lane&7) ^ (lane>>3);

  auto stageQ = [&](int buf, int qt){
    #pragma unroll
    for (int g=0; g<2; g++){
      int reg = w*2 + g;
      int r = reg*8 + (lane>>3);
      gload16(Qb + ((size_t)(b*TT + qt + r))*D_MODEL + h*64 + osrc*8,
              (char*)Qs[buf] + reg*1024);
    }
  };

  const int qstart = (k0 > qc*256) ? k0 : qc*256;
  const int qend   = (qc+1)*256;

  #pragma unroll
  for (int g=0; g<4; g++){
    int reg = w*4 + g;
    int r = reg*8 + (lane>>3);
    gload16(Kb + ((size_t)(b*TT + k0 + r))*D_MODEL + h*64 + osrc*8, (char*)Ks + reg*1024);
  }
  if (qstart < qend) stageQ(0, qstart);
  __syncthreads();

  bf16x8 bk[2][2];
  #pragma unroll
  for (int kb=0;kb<2;kb++)
    #pragma unroll
    for (int ks=0;ks<2;ks++){
      int r = w*32 + kb*16 + lr;
      bk[kb][ks] = *(const bf16x8*)((const char*)Ks + r*128 + (((ks*4+lg) ^ (r&7))*16));
    }
  f32x4 sacc[2] = {};
  int buf = 0;
  for (int qt = qstart; qt < qend; qt += 64){
    if (qt + 64 < qend) stageQ(buf^1, qt+64);
    const char* bufQ = (const char*)Qs[buf];
    const bool interior = (qt >= k0 + 128);
    #pragma unroll
    for (int qb=0;qb<4;qb++){
      bf16x8 aq[2];
      #pragma unroll
      for (int ks=0;ks<2;ks++){
        int r = qb*16 + lr;
        aq[ks] = *(const bf16x8*)(bufQ + r*128 + (((ks*4+lg) ^ (r&7))*16));
      }
      f32x4 sf[2] = {};
      #pragma unroll
      for (int ks=0;ks<2;ks++)
        #pragma unroll
        for (int kb=0;kb<2;kb++)
          sf[kb] = mfma16(aq[ks], bk[kb][ks], sf[kb]);
      #pragma unroll
      for (int kb=0;kb<2;kb++){
        int col = k0 + w*32 + kb*16 + lr;
        #pragma unroll
        for (int r=0;r<4;r++){
          float e = __expf(sf[kb][r] * 0.125f);
          if (!interior){
            int qg = qt + qb*16 + lg*4 + r;
            e = (qg >= col) ? e : 0.f;
          }
          sacc[kb][r] += e;
        }
      }
    }
    __syncthreads();
    buf ^= 1;
  }
  #pragma unroll
  for (int kb=0;kb<2;kb++){
    float s = sacc[kb][0] + sacc[kb][1] + sacc[kb][2] + sacc[kb][3];
    s += __shfl_xor(s, 16);
    s += __shfl_xor(s, 32);
    if (lg == 0){
      int col = k0 + w*32 + kb*16 + lr;
      partialS[((size_t)qc*BHN + bh)*TT + col] = s;
    }
  }
}

// ------------------------------------------------------------- Pass B: output
// O[q,:] = sum_{k<=q} [exp(S[q,k])/Z_k] * V[k,:].  Z_k combined from partialS
// in-block (inv_s LDS table) — vscale pass + kernel boundary eliminated.
// 8 waves x 16 q-rows (QBLK=128); K/V dbuf; swapped QK^T; wave-uniform
// skip of fully-masked diagonal tiles; setprio around MFMA clusters (T5).
__launch_bounds__(512)
__global__ void attn_out_kernel(const unsigned short* __restrict__ Qb,
                                const unsigned short* __restrict__ Kb,
                                const unsigned short* __restrict__ Vt,
                                const float* __restrict__ partialS,
                                unsigned short* __restrict__ O)
{
  __shared__ unsigned short Qs[128*64];      // 16KB
  __shared__ unsigned short Ks2[2][64*64];   // 8KB per buf
  __shared__ unsigned short Vs[2][64*64];
  __shared__ unsigned short Ps[128*64];      // 16KB (wave-private 16-row strips)
  __shared__ float inv_s[TT];                // 8KB; cols this block needs
  const int t = threadIdx.x, lane=t&63, w=t>>6;   // w in 0..7
  const int id = blockIdx.x;
  const int bh = id & 31;                 // XCD = bh%8 -> K/V in one XCD's L2
  const int qi = 15 - (id >> 5);          // heavy blocks first
  const int b = bh>>4, h = bh&15;
  const int q0 = qi*128;
  const int lr = lane&15, lg = lane>>4;
  const int osrc = (lane&7) ^ (lane>>3);

  auto stageKV = [&](int buf, int k0){
    int r = w*8 + (lane>>3);
    gload16(Kb + ((size_t)(b*TT + k0 + r))*D_MODEL + h*64 + osrc*8,
            (char*)Ks2[buf] + w*1024);
    gload16(Vt + ((size_t)(bh*HDIM + r))*TT + k0 + osrc*8,
            (char*)Vs[buf] + w*1024);
  };

  #pragma unroll
  for (int g=0; g<2; g++){
    int reg = w*2 + g;
    int r = reg*8 + (lane>>3);
    gload16(Qb + ((size_t)(b*TT + q0 + r))*D_MODEL + h*64 + osrc*8, (char*)Qs + reg*1024);
  }
  stageKV(0, 0);

  // combine partial column sums -> 1/Z for this block's columns [0, q0+128)
  const int ncols = q0 + 128;
  for (int c = t; c < ncols; c += 512){
    float s = 0.f;
    #pragma unroll
    for (int qc=0;qc<8;qc++) s += partialS[((size_t)qc*BHN + bh)*TT + c];
    inv_s[c] = 1.0f / s;
  }
  __syncthreads();

  bf16x8 aq[2];
  #pragma unroll
  for (int ks=0;ks<2;ks++){
    int r = w*16 + lr;
    aq[ks] = *(const bf16x8*)((const char*)Qs + r*128 + (((ks*4+lg) ^ (r&7))*16));
  }
  f32x4 oacc[4] = {};
  const int nkt = 2*qi + 2;
  int buf = 0;
  for (int kt=0; kt<nkt; kt++){
    int k0 = kt*64;
    if (kt+1 < nkt) stageKV(buf^1, k0+64);
    // wave-uniform: this wave's q-strip is [q0+w*16, q0+w*16+15]
    const bool active = (k0 <= q0 + w*16 + 15);
    if (active){
      const char* bufK = (const char*)Ks2[buf];
      const char* bufV = (const char*)Vs[buf];
      // S^T = K . Q^T : col = q (lr), row = k
      f32x4 sf[4] = {};
      __builtin_amdgcn_s_setprio(1);
      #pragma unroll
      for (int ks=0;ks<2;ks++)
        #pragma unroll
        for (int kb=0;kb<4;kb++){
          int r = kb*16 + lr;
          bf16x8 bk = *(const bf16x8*)(bufK + r*128 + (((ks*4+lg) ^ (r&7))*16));
          sf[kb] = mfma16(bk, aq[ks], sf[kb]);   // SWAPPED operands
        }
      __builtin_amdgcn_s_setprio(0);
      // P = exp(S)/Z_k; contiguous k-run of 4 -> one b64 LDS write
      const bool boundary = (k0 + 64 > q0 + w*16);
      const int prow = w*16 + lr;
      #pragma unroll
      for (int kb=0;kb<4;kb++){
        f32x4 inv4 = *(const f32x4*)&inv_s[k0 + kb*16 + lg*4];
        u16x4 vv;
        #pragma unroll
        for (int r=0;r<4;r++){
          float pv = __expf(sf[kb][r]*0.125f) * inv4[r];
          if (boundary){
            int kg = k0 + kb*16 + lg*4 + r;
            int qg = q0 + prow;
            pv = (qg >= kg) ? pv : 0.f;
          }
          vv[r] = f2b(pv);
        }
        *(u16x4*)((char*)Ps + ((prow*128 + kb*32 + lg*8) ^ ((prow&7)<<4))) = vv;
      }
      // (Ps rows wave-private; in-wave lgkmcnt ordering suffices)
      __builtin_amdgcn_s_setprio(1);
      #pragma unroll
      for (int ks=0;ks<2;ks++){
        bf16x8 pa = *(const bf16x8*)((const char*)Ps + prow*128 + (((ks*4+lg) ^ (prow&7))*16));
        #pragma unroll
        for (int db=0;db<4;db++){
          int r = db*16 + lr;
          bf16x8 bv = *(const bf16x8*)(bufV + r*128 + (((ks*4+lg) ^ (r&7))*16));
          oacc[db] = mfma16(pa, bv, oacc[db]);
        }
      }
      __builtin_amdgcn_s_setprio(0);
    }
    __syncthreads();
    buf ^= 1;
  }
  #pragma unroll
  for (int db=0;db<4;db++){
    int qg = q0 + w*16 + lg*4;
    int d  = db*16 + lr;
    #pragma unroll
    for (int r=0;r<4;r++)
      O[((size_t)(b*TT + qg + r))*D_MODEL + h*64 + d] = f2b(oacc[db][r]);
  }
}

// ---------------------------------------------------------------------- launch
extern "C" void kernel_launch(void* const* d_in, const int* in_sizes, int n_in,
                              void* d_out, int out_size, void* d_ws, size_t ws_size,
                              hipStream_t stream)
{
  (void)in_sizes; (void)n_in; (void)out_size; (void)ws_size;
  const float* q   = (const float*)d_in[0];
  const float* k   = (const float*)d_in[1];
  const float* v   = (const float*)d_in[2];
  const float* w_q = (const float*)d_in[3];
  const float* b_q = (const float*)d_in[4];
  const float* w_k = (const float*)d_in[5];
  const float* b_k = (const float*)d_in[6];
  const float* w_v = (const float*)d_in[7];
  const float* b_v = (const float*)d_in[8];
  const float* w_o = (const float*)d_in[9];
  const float* b_o = (const float*)d_in[10];

  char* p = (char*)d_ws;
  auto carve = [&](size_t bytes)->char* {
    char* r = p; p += (bytes + 255) & ~(size_t)255; return r;
  };
  unsigned short* Xq  = (unsigned short*)carve((size_t)MM*D_MODEL*2);
  unsigned short* Xk  = (unsigned short*)carve((size_t)MM*D_MODEL*2);
  unsigned short* Xv  = (unsigned short*)carve((size_t)MM*D_MODEL*2);
  unsigned short* Wtq = (unsigned short*)carve((size_t)D_MODEL*D_MODEL*2);
  unsigned short* Wtk = (unsigned short*)carve((size_t)D_MODEL*D_MODEL*2);
  unsigned short* Wtv = (unsigned short*)carve((size_t)D_MODEL*D_MODEL*2);
  unsigned short* Wto = (unsigned short*)carve((size_t)D_MODEL*D_MODEL*2);
  unsigned short* Qb  = (unsigned short*)carve((size_t)MM*D_MODEL*2);
  unsigned short* Kb  = (unsigned short*)carve((size_t)MM*D_MODEL*2);
  unsigned short* Vt  = (unsigned short*)carve((size_t)MM*D_MODEL*2);
  unsigned short* Ob  = (unsigned short*)carve((size_t)MM*D_MODEL*2);
  float* partialS = (float*)carve((size_t)8*BHN*TT*4);

  pre_kernel<<<dim3(6144 + 4096), 256, 0, stream>>>(q, k, v, Xq, Xk, Xv,
                                                    w_q, w_k, w_v, w_o,
                                                    Wtq, Wtk, Wtv, Wto);

  proj_gemm_kernel<<<dim3(768), 256, 0, stream>>>(Xq, Xk, Xv, Wtq, Wtk, Wtv,
                                                  b_q, b_k, b_v, Qb, Kb, Vt);

  col_stats_kernel<<<dim3(8*16*BHN), 256, 0, stream>>>(Qb, Kb, partialS);

  attn_out_kernel<<<dim3((TT/128)*BHN), 512, 0, stream>>>(Qb, Kb, Vt, partialS, Ob);

  out_gemm_kernel<<<dim3(512), 256, 0, stream>>>(Ob, Wto, b_o, (float*)d_out);
}

// Round 11
// 141.616 us; speedup vs baseline: 1.0709x; 1.0067x over previous
//
#include <hip/hip_runtime.h>
#include <hip/hip_bf16.h>
#include <cstdint>
#include <cstddef>

#define D_MODEL 1024
#define NHEAD   16
#define HDIM    64
#define BB      2
#define TT      2048
#define MM      (BB*TT)    // 4096 rows
#define BHN     (BB*NHEAD) // 32

typedef __attribute__((ext_vector_type(8))) __bf16 bf16x8;
typedef __attribute__((ext_vector_type(4))) float  f32x4;
typedef __attribute__((ext_vector_type(8))) unsigned short u16x8;
typedef __attribute__((ext_vector_type(4))) unsigned short u16x4;

__device__ __forceinline__ unsigned short f2b(float f){
  __bf16 b = (__bf16)f;
  return __builtin_bit_cast(unsigned short, b);
}

__device__ __forceinline__ f32x4 mfma16(bf16x8 a, bf16x8 b, f32x4 c){
  return __builtin_amdgcn_mfma_f32_16x16x32_bf16(a, b, c, 0, 0, 0);
}

// async global->LDS, 16B per lane; LDS dest = wave-uniform base + lane*16.
__device__ __forceinline__ void gload16(const void* g, void* lds){
  __builtin_amdgcn_global_load_lds((const __attribute__((address_space(1))) void*)g,
                                   (__attribute__((address_space(3))) void*)lds, 16, 0, 0);
}

// -------------------- fused preprocessing: cvt q/k/v (blocks 0..6143) +
// -------------------- transpose 4 weights (blocks 6144..10239)
__global__ void pre_kernel(const float* __restrict__ q, const float* __restrict__ k,
                           const float* __restrict__ v,
                           unsigned short* __restrict__ Xq, unsigned short* __restrict__ Xk,
                           unsigned short* __restrict__ Xv,
                           const float* __restrict__ W0, const float* __restrict__ W1,
                           const float* __restrict__ W2, const float* __restrict__ W3,
                           unsigned short* __restrict__ T0, unsigned short* __restrict__ T1,
                           unsigned short* __restrict__ T2, unsigned short* __restrict__ T3)
{
  __shared__ float tile[32][33];
  const int id = blockIdx.x;
  if (id < 6144){
    const int z = id / 2048, ib = id - z*2048;
    const float* x = z==0 ? q : z==1 ? k : v;
    unsigned short* y = z==0 ? Xq : z==1 ? Xk : Xv;
    size_t i = (size_t)ib*256 + threadIdx.x;
    const float4* p = (const float4*)(x + i*8);
    float4 a = p[0], b = p[1];
    u16x8 o;
    o[0]=f2b(a.x); o[1]=f2b(a.y); o[2]=f2b(a.z); o[3]=f2b(a.w);
    o[4]=f2b(b.x); o[5]=f2b(b.y); o[6]=f2b(b.z); o[7]=f2b(b.w);
    *(u16x8*)(y + i*8) = o;
  } else {
    const int tid = id - 6144;
    const int z = tid >> 10;
    const int by = (tid >> 5) & 31, bx = tid & 31;
    const float* W = z==0 ? W0 : z==1 ? W1 : z==2 ? W2 : W3;
    unsigned short* Wt = z==0 ? T0 : z==1 ? T1 : z==2 ? T2 : T3;
    const int tx = threadIdx.x & 31, ty = threadIdx.x >> 5;
    const int x0 = bx*32, y0 = by*32;
    #pragma unroll
    for (int i=0;i<4;i++)
      tile[ty + i*8][tx] = W[(size_t)(y0 + ty + i*8)*D_MODEL + x0 + tx];
    __syncthreads();
    #pragma unroll
    for (int i=0;i<4;i++)
      Wt[(size_t)(x0 + ty + i*8)*D_MODEL + y0 + tx] = f2b(tile[tx][ty + i*8]);
  }
}

// ---------------------------------------------------------------- proj GEMM
// C[M][N] = (A[M][K] * Bt[N][K]^T + bias) * oscale, 128x128, BK=32, dbuf.
// oscale=0.125 for Q folds the softmax 1/sqrt(dh) into the projection (exact pow2).
// LDS[r][u] = G[r][u ^ ((r>>1)&3)]; read chunk crd = lg ^ ((lr>>1)&3).
// mode 0: bf16 row-major out. mode 1: V-transposed Vt[b][h][d][t] bf16.
__device__ __forceinline__ void gemm_body(const unsigned short* __restrict__ A,
                                          const unsigned short* __restrict__ Bt,
                                          const float* __restrict__ bias,
                                          void* __restrict__ Cout, const int mode,
                                          const int m0, const int n0, const float oscale)
{
  constexpr int K = D_MODEL, N = D_MODEL;
  __shared__ unsigned short As[2][128*32];   // 8KB per buf
  __shared__ unsigned short Bs[2][128*32];
  const int t = threadIdx.x, lane = t&63, w = t>>6;
  const int wr = w>>1, wc = w&1, lr = lane&15, lg = lane>>4;
  const int srow = lane>>2;                      // row within 16-row region
  const int schunk = (lane&3) ^ ((lane>>3)&3);   // involution source chunk
  const int crd = lg ^ ((lr>>1)&3);              // read chunk (lane-const)
  f32x4 acc[4][4] = {};

  auto stage = [&](int buf, int k0){
    #pragma unroll
    for (int g=0; g<2; g++){
      int reg = w*2 + g;                         // 1KB region = 16 rows x 64B
      int r = reg*16 + srow;
      gload16(A  + (size_t)(m0+r)*K + k0 + schunk*8, (char*)As[buf] + reg*1024);
      gload16(Bt + (size_t)(n0+r)*K + k0 + schunk*8, (char*)Bs[buf] + reg*1024);
    }
  };

  stage(0, 0);
  __syncthreads();
  int buf = 0;
  for (int ks = 0; ks < 32; ++ks){
    if (ks < 31) stage(buf^1, (ks+1)*32);
    const char* bufA = (const char*)As[buf];
    const char* bufB = (const char*)Bs[buf];
    bf16x8 af[4], bfv[4];
    #pragma unroll
    for (int mi=0;mi<4;mi++){
      int r = wr*64 + mi*16 + lr;
      af[mi] = *(const bf16x8*)(bufA + r*64 + crd*16);
    }
    #pragma unroll
    for (int ni=0;ni<4;ni++){
      int r = wc*64 + ni*16 + lr;
      bfv[ni] = *(const bf16x8*)(bufB + r*64 + crd*16);
    }
    #pragma unroll
    for (int mi=0;mi<4;mi++)
      #pragma unroll
      for (int ni=0;ni<4;ni++)
        acc[mi][ni] = mfma16(af[mi], bfv[ni], acc[mi][ni]);
    __syncthreads();
    buf ^= 1;
  }

  #pragma unroll
  for (int mi=0;mi<4;mi++){
    #pragma unroll
    for (int ni=0;ni<4;ni++){
      int n = n0 + wc*64 + ni*16 + lr;
      int mbase = m0 + wr*64 + mi*16 + lg*4;
      float bv = bias[n];
      if (mode == 0){
        unsigned short* Cb = (unsigned short*)Cout;
        #pragma unroll
        for (int r=0;r<4;r++) Cb[(size_t)(mbase+r)*N + n] = f2b((acc[mi][ni][r] + bv)*oscale);
      } else {
        unsigned short* Vt = (unsigned short*)Cout;
        int h = n >> 6, d = n & 63;
        int b = mbase >> 11;
        int tq = mbase & (TT-1);
        u16x4 vv;
        #pragma unroll
        for (int r=0;r<4;r++) vv[r] = f2b(acc[mi][ni][r] + bv);
        *(u16x4*)(Vt + ((size_t)((b*NHEAD + h)*HDIM + d))*TT + tq) = vv;
      }
    }
  }
}

// proj: flat grid 768 = 8 xcd x 8 n x 4 m_inner x 3 z (T1 XCD-locality for A-panels)
__launch_bounds__(256)
__global__ void proj_gemm_kernel(const unsigned short* __restrict__ Xq,
                                 const unsigned short* __restrict__ Xk,
                                 const unsigned short* __restrict__ Xv,
                                 const unsigned short* __restrict__ Wtq,
                                 const unsigned short* __restrict__ Wtk,
                                 const unsigned short* __restrict__ Wtv,
                                 const float* __restrict__ b_q, const float* __restrict__ b_k,
                                 const float* __restrict__ b_v,
                                 unsigned short* __restrict__ Qb, unsigned short* __restrict__ Kb,
                                 unsigned short* __restrict__ Vt)
{
  const int id = blockIdx.x;
  const int xcd = id & 7, r2 = id >> 3;
  const int n = r2 & 7, mz = r2 >> 3;
  const int m = (mz & 3)*8 + xcd, z = mz >> 2;
  const unsigned short* A  = z==0 ? Xq : z==1 ? Xk : Xv;
  const unsigned short* Bt = z==0 ? Wtq : z==1 ? Wtk : Wtv;
  const float* bias = z==0 ? b_q : z==1 ? b_k : b_v;
  void* C = z==0 ? (void*)Qb : z==1 ? (void*)Kb : (void*)Vt;
  gemm_body(A, Bt, bias, C, z==2 ? 1 : 0, m*128, n*128, z==0 ? 0.125f : 1.0f);
}

// out-proj: 64x128 tiles, 512 blocks (2/CU), f32 output, dbuf + gload16
__launch_bounds__(256)
__global__ void out_gemm_kernel(const unsigned short* __restrict__ Ob,
                                const unsigned short* __restrict__ Wto,
                                const float* __restrict__ b_o, float* __restrict__ out)
{
  constexpr int K = D_MODEL, N = D_MODEL;
  __shared__ unsigned short As[2][64*32];    // 4KB per buf
  __shared__ unsigned short Bs[2][128*32];   // 8KB per buf
  const int id = blockIdx.x;
  const int xcd = id & 7, r2 = id >> 3;
  const int n0 = (r2 & 7)*128, m0 = ((r2 >> 3)*8 + xcd)*64;
  const int t = threadIdx.x, lane = t&63, w = t>>6;
  const int wr = w>>1, wc = w&1, lr = lane&15, lg = lane>>4;
  const int srow = lane>>2;
  const int schunk = (lane&3) ^ ((lane>>3)&3);
  const int crd = lg ^ ((lr>>1)&3);
  f32x4 acc[2][4] = {};

  auto stage = [&](int buf, int k0){
    { int r = w*16 + srow;
      gload16(Ob + (size_t)(m0+r)*K + k0 + schunk*8, (char*)As[buf] + w*1024); }
    #pragma unroll
    for (int g=0; g<2; g++){
      int reg = w*2 + g;
      int r = reg*16 + srow;
      gload16(Wto + (size_t)(n0+r)*K + k0 + schunk*8, (char*)Bs[buf] + reg*1024);
    }
  };

  stage(0, 0);
  __syncthreads();
  int buf = 0;
  for (int ks = 0; ks < 32; ++ks){
    if (ks < 31) stage(buf^1, (ks+1)*32);
    const char* bufA = (const char*)As[buf];
    const char* bufB = (const char*)Bs[buf];
    bf16x8 af[2], bfv[4];
    #pragma unroll
    for (int mi=0;mi<2;mi++){
      int r = wr*32 + mi*16 + lr;
      af[mi] = *(const bf16x8*)(bufA + r*64 + crd*16);
    }
    #pragma unroll
    for (int ni=0;ni<4;ni++){
      int r = wc*64 + ni*16 + lr;
      bfv[ni] = *(const bf16x8*)(bufB + r*64 + crd*16);
    }
    #pragma unroll
    for (int mi=0;mi<2;mi++)
      #pragma unroll
      for (int ni=0;ni<4;ni++)
        acc[mi][ni] = mfma16(af[mi], bfv[ni], acc[mi][ni]);
    __syncthreads();
    buf ^= 1;
  }

  #pragma unroll
  for (int mi=0;mi<2;mi++){
    #pragma unroll
    for (int ni=0;ni<4;ni++){
      int n = n0 + wc*64 + ni*16 + lr;
      int mbase = m0 + wr*32 + mi*16 + lg*4;
      float bv = b_o[n];
      #pragma unroll
      for (int r=0;r<4;r++) out[(size_t)(mbase+r)*N + n] = acc[mi][ni][r] + bv;
    }
  }
}

// ------------------------------------------------------- Pass A: column sums
// partialS[qc][bh][col] = sum_{q in 256-chunk qc, q>=col} exp(S[q,col])
// (Q pre-scaled by 1/8 in proj — no per-element scale here.)
__launch_bounds__(256)
__global__ void col_stats_kernel(const unsigned short* __restrict__ Qb,
                                 const unsigned short* __restrict__ Kb,
                                 float* __restrict__ partialS)
{
  __shared__ unsigned short Ks[128*64];      // 16KB static
  __shared__ unsigned short Qs[2][64*64];    // 8KB per buf
  const int t = threadIdx.x, lane = t&63, w = t>>6;
  const int id = blockIdx.x;
  const int bh = id & 31, pair = id >> 5;   // XCD = bh%8 -> per-bh L2 locality
  const int kb_ = pair & 15, qc = pair >> 4;
  const int b = bh >> 4, h = bh & 15;
  const int k0 = kb_ * 128;
  const int lr = lane&15, lg = lane>>4;
  const int osrc = (lane&7) ^ (lane>>3);

  auto stageQ = [&](int buf, int qt){
    #pragma unroll
    for (int g=0; g<2; g++){
      int reg = w*2 + g;
      int r = reg*8 + (lane>>3);
      gload16(Qb + ((size_t)(b*TT + qt + r))*D_MODEL + h*64 + osrc*8,
              (char*)Qs[buf] + reg*1024);
    }
  };

  const int qstart = (k0 > qc*256) ? k0 : qc*256;
  const int qend   = (qc+1)*256;

  #pragma unroll
  for (int g=0; g<4; g++){
    int reg = w*4 + g;
    int r = reg*8 + (lane>>3);
    gload16(Kb + ((size_t)(b*TT + k0 + r))*D_MODEL + h*64 + osrc*8, (char*)Ks + reg*1024);
  }
  if (qstart < qend) stageQ(0, qstart);
  __syncthreads();

  bf16x8 bk[2][2];
  #pragma unroll
  for (int kb=0;kb<2;kb++)
    #pragma unroll
    for (int ks=0;ks<2;ks++){
      int r = w*32 + kb*16 + lr;
      bk[kb][ks] = *(const bf16x8*)((const char*)Ks + r*128 + (((ks*4+lg) ^ (r&7))*16));
    }
  f32x4 sacc[2] = {};
  int buf = 0;
  for (int qt = qstart; qt < qend; qt += 64){
    if (qt + 64 < qend) stageQ(buf^1, qt+64);
    const char* bufQ = (const char*)Qs[buf];
    const bool interior = (qt >= k0 + 128);
    #pragma unroll
    for (int qb=0;qb<4;qb++){
      bf16x8 aq[2];
      #pragma unroll
      for (int ks=0;ks<2;ks++){
        int r = qb*16 + lr;
        aq[ks] = *(const bf16x8*)(bufQ + r*128 + (((ks*4+lg) ^ (r&7))*16));
      }
      f32x4 sf[2] = {};
      #pragma unroll
      for (int ks=0;ks<2;ks++)
        #pragma unroll
        for (int kb=0;kb<2;kb++)
          sf[kb] = mfma16(aq[ks], bk[kb][ks], sf[kb]);
      #pragma unroll
      for (int kb=0;kb<2;kb++){
        int col = k0 + w*32 + kb*16 + lr;
        #pragma unroll
        for (int r=0;r<4;r++){
          float e = __expf(sf[kb][r]);
          if (!interior){
            int qg = qt + qb*16 + lg*4 + r;
            e = (qg >= col) ? e : 0.f;
          }
          sacc[kb][r] += e;
        }
      }
    }
    __syncthreads();
    buf ^= 1;
  }
  #pragma unroll
  for (int kb=0;kb<2;kb++){
    float s = sacc[kb][0] + sacc[kb][1] + sacc[kb][2] + sacc[kb][3];
    s += __shfl_xor(s, 16);
    s += __shfl_xor(s, 32);
    if (lg == 0){
      int col = k0 + w*32 + kb*16 + lr;
      partialS[((size_t)qc*BHN + bh)*TT + col] = s;
    }
  }
}

// ------------------------------------------------------------- Pass B: output
// O[q,:] = sum_{k<=q} [exp(S[q,k])/Z_k] * V[k,:].
// BALANCED PAIRING: block owns strips qi=pr (light) and qi=31-pr (heavy) over
// one shared k-sweep -> constant 33 tile-strips/block, K/V staged once for both.
// 4 waves x 16 q-rows per strip; K/V dbuf; swapped QK^T; setprio (T5).
__launch_bounds__(256)
__global__ void attn_out_kernel(const unsigned short* __restrict__ Qb,
                                const unsigned short* __restrict__ Kb,
                                const unsigned short* __restrict__ Vt,
                                const float* __restrict__ partialS,
                                unsigned short* __restrict__ O)
{
  __shared__ unsigned short Qs[2][64*64];    // 8KB per strip
  __shared__ unsigned short Ks2[2][64*64];   // 8KB per buf
  __shared__ unsigned short Vs[2][64*64];
  __shared__ unsigned short Ps[64*64];       // 8KB (wave-private rows, strips sequential)
  __shared__ float inv_s[TT];                // 8KB
  const int t = threadIdx.x, lane=t&63, w=t>>6;   // w in 0..3
  const int id = blockIdx.x;
  const int bh = id & 31;                 // XCD = bh%8 -> K/V in one XCD's L2
  const int pr = id >> 5;                 // 0..15
  const int b = bh>>4, h = bh&15;
  const int q0A = pr*64, q0B = (31-pr)*64;
  const int nkt = (31-pr) + 1;            // k-tiles for heavy strip
  const int lr = lane&15, lg = lane>>4;
  const int osrc = (lane&7) ^ (lane>>3);

  auto stageQ = [&](int s, int q0){
    #pragma unroll
    for (int g=0; g<2; g++){
      int reg = w*2 + g;
      int r = reg*8 + (lane>>3);
      gload16(Qb + ((size_t)(b*TT + q0 + r))*D_MODEL + h*64 + osrc*8,
              (char*)Qs[s] + reg*1024);
    }
  };
  auto stageKV = [&](int buf, int k0){
    #pragma unroll
    for (int g=0; g<2; g++){
      int reg = w*2 + g;
      int r = reg*8 + (lane>>3);
      gload16(Kb + ((size_t)(b*TT + k0 + r))*D_MODEL + h*64 + osrc*8,
              (char*)Ks2[buf] + reg*1024);
      gload16(Vt + ((size_t)(bh*HDIM + r))*TT + k0 + osrc*8,
              (char*)Vs[buf] + reg*1024);
    }
  };

  stageQ(0, q0A);
  stageQ(1, q0B);
  stageKV(0, 0);

  // combine partial column sums -> 1/Z for cols [0, nkt*64)
  const int ncols = nkt*64;
  for (int c = t; c < ncols; c += 256){
    float s = 0.f;
    #pragma unroll
    for (int qc=0;qc<8;qc++) s += partialS[((size_t)qc*BHN + bh)*TT + c];
    inv_s[c] = 1.0f / s;
  }
  __syncthreads();

  bf16x8 aqA[2], aqB[2];
  #pragma unroll
  for (int ks=0;ks<2;ks++){
    int r = w*16 + lr;
    aqA[ks] = *(const bf16x8*)((const char*)Qs[0] + r*128 + (((ks*4+lg) ^ (r&7))*16));
    aqB[ks] = *(const bf16x8*)((const char*)Qs[1] + r*128 + (((ks*4+lg) ^ (r&7))*16));
  }
  f32x4 oaccA[4] = {}, oaccB[4] = {};
  const int prow = w*16 + lr;

  // one strip's tile-step: QK^T -> P=exp(S)/Z -> PV accumulate
  auto strip_step = [&](const bf16x8* aq, f32x4* oacc, int q0, int k0,
                        const char* bufK, const char* bufV){
    f32x4 sf[4] = {};
    __builtin_amdgcn_s_setprio(1);
    #pragma unroll
    for (int ks=0;ks<2;ks++)
      #pragma unroll
      for (int kb=0;kb<4;kb++){
        int r = kb*16 + lr;
        bf16x8 bk = *(const bf16x8*)(bufK + r*128 + (((ks*4+lg) ^ (r&7))*16));
        sf[kb] = mfma16(bk, aq[ks], sf[kb]);   // SWAPPED operands -> S^T
      }
    __builtin_amdgcn_s_setprio(0);
    const bool boundary = (k0 + 64 > q0 + w*16);
    #pragma unroll
    for (int kb=0;kb<4;kb++){
      f32x4 inv4 = *(const f32x4*)&inv_s[k0 + kb*16 + lg*4];
      u16x4 vv;
      #pragma unroll
      for (int r=0;r<4;r++){
        float pv = __expf(sf[kb][r]) * inv4[r];
        if (boundary){
          int kg = k0 + kb*16 + lg*4 + r;
          pv = (q0 + prow >= kg) ? pv : 0.f;
        }
        vv[r] = f2b(pv);
      }
      *(u16x4*)((char*)Ps + ((prow*128 + kb*32 + lg*8) ^ ((prow&7)<<4))) = vv;
    }
    __builtin_amdgcn_s_setprio(1);
    #pragma unroll
    for (int ks=0;ks<2;ks++){
      bf16x8 pa = *(const bf16x8*)((const char*)Ps + prow*128 + (((ks*4+lg) ^ (prow&7))*16));
      #pragma unroll
      for (int db=0;db<4;db++){
        int r = db*16 + lr;
        bf16x8 bv = *(const bf16x8*)(bufV + r*128 + (((ks*4+lg) ^ (r&7))*16));
        oacc[db] = mfma16(pa, bv, oacc[db]);
      }
    }
    __builtin_amdgcn_s_setprio(0);
  };

  int buf = 0;
  for (int kt=0; kt<nkt; kt++){
    int k0 = kt*64;
    if (kt+1 < nkt) stageKV(buf^1, k0+64);
    const char* bufK = (const char*)Ks2[buf];
    const char* bufV = (const char*)Vs[buf];
    // strip A active while its diagonal not passed (wave-uniform)
    if (k0 <= q0A + w*16 + 15)
      strip_step(aqA, oaccA, q0A, k0, bufK, bufV);
    // strip B active for all kt in [0, nkt)
    strip_step(aqB, oaccB, q0B, k0, bufK, bufV);
    __syncthreads();
    buf ^= 1;
  }
  #pragma unroll
  for (int db=0;db<4;db++){
    int d = db*16 + lr;
    int qgA = q0A + w*16 + lg*4;
    int qgB = q0B + w*16 + lg*4;
    #pragma unroll
    for (int r=0;r<4;r++){
      O[((size_t)(b*TT + qgA + r))*D_MODEL + h*64 + d] = f2b(oaccA[db][r]);
      O[((size_t)(b*TT + qgB + r))*D_MODEL + h*64 + d] = f2b(oaccB[db][r]);
    }
  }
}

// ---------------------------------------------------------------------- launch
extern "C" void kernel_launch(void* const* d_in, const int* in_sizes, int n_in,
                              void* d_out, int out_size, void* d_ws, size_t ws_size,
                              hipStream_t stream)
{
  (void)in_sizes; (void)n_in; (void)out_size; (void)ws_size;
  const float* q   = (const float*)d_in[0];
  const float* k   = (const float*)d_in[1];
  const float* v   = (const float*)d_in[2];
  const float* w_q = (const float*)d_in[3];
  const float* b_q = (const float*)d_in[4];
  const float* w_k = (const float*)d_in[5];
  const float* b_k = (const float*)d_in[6];
  const float* w_v = (const float*)d_in[7];
  const float* b_v = (const float*)d_in[8];
  const float* w_o = (const float*)d_in[9];
  const float* b_o = (const float*)d_in[10];

  char* p = (char*)d_ws;
  auto carve = [&](size_t bytes)->char* {
    char* r = p; p += (bytes + 255) & ~(size_t)255; return r;
  };
  unsigned short* Xq  = (unsigned short*)carve((size_t)MM*D_MODEL*2);
  unsigned short* Xk  = (unsigned short*)carve((size_t)MM*D_MODEL*2);
  unsigned short* Xv  = (unsigned short*)carve((size_t)MM*D_MODEL*2);
  unsigned short* Wtq = (unsigned short*)carve((size_t)D_MODEL*D_MODEL*2);
  unsigned short* Wtk = (unsigned short*)carve((size_t)D_MODEL*D_MODEL*2);
  unsigned short* Wtv = (unsigned short*)carve((size_t)D_MODEL*D_MODEL*2);
  unsigned short* Wto = (unsigned short*)carve((size_t)D_MODEL*D_MODEL*2);
  unsigned short* Qb  = (unsigned short*)carve((size_t)MM*D_MODEL*2);
  unsigned short* Kb  = (unsigned short*)carve((size_t)MM*D_MODEL*2);
  unsigned short* Vt  = (unsigned short*)carve((size_t)MM*D_MODEL*2);
  unsigned short* Ob  = (unsigned short*)carve((size_t)MM*D_MODEL*2);
  float* partialS = (float*)carve((size_t)8*BHN*TT*4);

  pre_kernel<<<dim3(6144 + 4096), 256, 0, stream>>>(q, k, v, Xq, Xk, Xv,
                                                    w_q, w_k, w_v, w_o,
                                                    Wtq, Wtk, Wtv, Wto);

  proj_gemm_kernel<<<dim3(768), 256, 0, stream>>>(Xq, Xk, Xv, Wtq, Wtk, Wtv,
                                                  b_q, b_k, b_v, Qb, Kb, Vt);

  col_stats_kernel<<<dim3(8*16*BHN), 256, 0, stream>>>(Qb, Kb, partialS);

  attn_out_kernel<<<dim3(16*BHN), 256, 0, stream>>>(Qb, Kb, Vt, partialS, Ob);

  out_gemm_kernel<<<dim3(512), 256, 0, stream>>>(Ob, Wto, b_o, (float*)d_out);
}